// Round 7
// baseline (416.252 us; speedup 1.0000x reference)
//
#include <hip/hip_runtime.h>
#include <hip/hip_bf16.h>
#include <stdint.h>

// Problem dims
#define M_DIM 4096      // 2*2048 rows of x
#define K_DIM 4096
#define N_DIM 11008
#define KP    2048      // K/2 packed int32 per w row

// ---------------- 8-phase 256x256 GEMM geometry ----------------
#define BK2   64
#define NKT   (K_DIM/BK2)        // 64 K-tiles
#define NTM2  (M_DIM/256)        // 16
#define NTN2  (N_DIM/256)        // 43
#define NBLK2 (NTM2*NTN2)        // 688  (%8==0 -> bijective XCD swizzle)
#define HT_BYTES 16384           // half-tile: 128 rows x 64 bf16 (fragment-major)

// ---------------- 128x128 fallback geometry ----------------
#define BM 128
#define BN 128
#define BK 64
#define NTM (M_DIM/BM)
#define NTN (N_DIM/BN)
#define NBLK (NTM*NTN)

typedef __attribute__((ext_vector_type(8)))  short bf16x8;
typedef __attribute__((ext_vector_type(4)))  float f32x4;
typedef __attribute__((ext_vector_type(16))) float f32x16;
typedef __attribute__((ext_vector_type(8)))  unsigned short u16x8;

typedef const void __attribute__((address_space(1)))* gas_ptr;
typedef void __attribute__((address_space(3)))* las_ptr;

__device__ __forceinline__ void async_copy16(void* lds, const void* g) {
  __builtin_amdgcn_global_load_lds((gas_ptr)g, (las_ptr)lds, 16, 0, 0);
}

__device__ __forceinline__ unsigned short f2bf_rne(float f) {
  uint32_t u = __builtin_bit_cast(uint32_t, f);
  u += 0x7FFFu + ((u >> 16) & 1u);
  return (unsigned short)(u >> 16);
}
__device__ __forceinline__ unsigned short i2bf(int v) {
  float f = (float)v;
  return (unsigned short)(__builtin_bit_cast(uint32_t, f) >> 16);
}
__device__ __forceinline__ int sx4(int b, int which) {
  return ((int)((uint32_t)b << (28 - 4 * which))) >> 28;
}

// ---------------- pre-pass: fragment-major half-tile images ----------------
// Half-tile image (16KB = 1024 x 16B chunks): chunk c = msub*256 + ks*64 + kg*32 + l31
// holds T[msub*32 + l31][ks*16 + kg*8 .. +8]  (T = 128-row x 64-col bf16 tile).
// A wave's MFMA fragment read (fixed msub,ks) = 64 lanes x 16B CONTIGUOUS -> 0 conflicts.

__global__ __launch_bounds__(256) void cvt_x_tiled(const float* __restrict__ x,
                                                   unsigned short* __restrict__ wsA) {
  const int total = NTM2 * NKT * 2 * 1024;   // 16B chunks, source-ordered
  for (int i = blockIdx.x * blockDim.x + threadIdx.x; i < total;
       i += gridDim.x * blockDim.x) {
    int rc  = i & 1023;            // source chunk within half-tile
    int h   = (i >> 10) & 1;
    int kt  = (i >> 11) & 63;
    int tm  = i >> 17;
    int row = rc >> 3, e8 = rc & 7;         // 8 consecutive f32 per chunk (coalesced)
    const float* src = x + (size_t)(tm * 256 + h * 128 + row) * K_DIM + kt * 64 + e8 * 8;
    float4 v0 = *(const float4*)src;
    float4 v1 = *(const float4*)(src + 4);
    u16x8 r;
    r[0] = f2bf_rne(v0.x); r[1] = f2bf_rne(v0.y); r[2] = f2bf_rne(v0.z); r[3] = f2bf_rne(v0.w);
    r[4] = f2bf_rne(v1.x); r[5] = f2bf_rne(v1.y); r[6] = f2bf_rne(v1.z); r[7] = f2bf_rne(v1.w);
    int c = (row >> 5) * 256 + (e8 >> 1) * 64 + (e8 & 1) * 32 + (row & 31);
    *(u16x8*)((char*)wsA + (size_t)(i >> 10) * HT_BYTES + c * 16) = r;
  }
}

__global__ __launch_bounds__(256) void deq_w_tiled(const int* __restrict__ wp,
                                                   unsigned short* __restrict__ wsB) {
  const int total = NTN2 * NKT * 2 * 1024;
  for (int i = blockIdx.x * blockDim.x + threadIdx.x; i < total;
       i += gridDim.x * blockDim.x) {
    int rc  = i & 1023;
    int h   = (i >> 10) & 1;
    int kt  = (i >> 11) & 63;
    int tn  = i >> 17;
    int row = rc >> 3, e8 = rc & 7;
    int4 b = *(const int4*)(wp + (size_t)(tn * 256 + h * 128 + row) * KP + kt * 32 + e8 * 4);
    u16x8 r;
    r[0] = i2bf(sx4(b.x, 0)); r[1] = i2bf(sx4(b.x, 1));
    r[2] = i2bf(sx4(b.y, 0)); r[3] = i2bf(sx4(b.y, 1));
    r[4] = i2bf(sx4(b.z, 0)); r[5] = i2bf(sx4(b.z, 1));
    r[6] = i2bf(sx4(b.w, 0)); r[7] = i2bf(sx4(b.w, 1));
    int c = (row >> 5) * 256 + (e8 >> 1) * 64 + (e8 & 1) * 32 + (row & 31);
    *(u16x8*)((char*)wsB + (size_t)(i >> 10) * HT_BYTES + c * 16) = r;
  }
}

// ------- 8-phase 256x256 GEMM, 32x32x16, 2-phase-early reads + counted waits -------
__global__ __launch_bounds__(512, 2)
void qgemm8(const unsigned short* __restrict__ wsA, const unsigned short* __restrict__ wsB,
            const float* __restrict__ scales, const float* __restrict__ bias,
            float* __restrict__ out) {
  __shared__ __align__(16) char smem[131072];  // 2 buf x (A 32KB + B 32KB)

  const int tid  = threadIdx.x;
  const int lane = tid & 63, wid = tid >> 6;
  const int wr = wid >> 2, wc = wid & 3;       // 2x4 wave grid; per-wave 128x64
  const int l31 = lane & 31, kg = lane >> 5;

  int bid = blockIdx.x;
  int id  = (bid & 7) * (NBLK2 / 8) + (bid >> 3);   // bijective XCD chunking
  int tm  = id & (NTM2 - 1), tn = id >> 4;          // tn-major: B panel shared per XCD

  const char* gA = (const char*)wsA + (size_t)tm * (NKT * 2) * HT_BYTES;
  const char* gB = (const char*)wsB + (size_t)tn * (NKT * 2) * HT_BYTES;

  // Per-lane fragment bases: read group = 64 lanes x 16B contiguous (conflict-free)
  const char* baseA = smem + wr * HT_BYTES + lane * 16;
  const char* baseB = smem + 32768 + (wc >> 1) * HT_BYTES + lane * 16;

#define STAGE(ldsoff, src) do { \
    async_copy16(smem + (ldsoff) + (wid * 64) * 16, (src) + (wid * 64 + lane) * 16); \
    async_copy16(smem + (ldsoff) + (512 + wid * 64) * 16, (src) + (512 + wid * 64 + lane) * 16); \
  } while (0)
#define STAGE_A(buf, h, kt) STAGE((buf) * 65536 + (h) * HT_BYTES, gA + ((kt) * 2 + (h)) * HT_BYTES)
#define STAGE_B(buf, h, kt) STAGE((buf) * 65536 + 32768 + (h) * HT_BYTES, gB + ((kt) * 2 + (h)) * HT_BYTES)

  f32x16 acc[4][2] = {};   // [msub 0..3][nsub 0..1], 128 regs
  bf16x8 aS0[2][4], aS1[2][4];   // A frag sets: [msub-in-pair][kstep]
  bf16x8 bS0[4], bS1[4];         // B frag sets: [kstep]

#define LDA_SET(dst, buf, sel) do { \
    _Pragma("unroll") for (int i = 0; i < 2; ++i) \
    _Pragma("unroll") for (int ks = 0; ks < 4; ++ks) \
      dst[i][ks] = *(const bf16x8*)(baseA + (buf) * 65536 + ((sel) * 2 + i) * 4096 + ks * 1024); \
  } while (0)
#define LDA_HALF(dst, buf, sel, hf) do { \
    _Pragma("unroll") for (int ks = 0; ks < 4; ++ks) \
      dst[hf][ks] = *(const bf16x8*)(baseA + (buf) * 65536 + ((sel) * 2 + (hf)) * 4096 + ks * 1024); \
  } while (0)
#define LDB_SET(dst, buf, bn) do { \
    _Pragma("unroll") for (int ks = 0; ks < 4; ++ks) \
      dst[ks] = *(const bf16x8*)(baseB + (buf) * 65536 + ((wc & 1) * 2 + (bn)) * 4096 + ks * 1024); \
  } while (0)
#define MMQ(aS, bS, sel, bn) do { \
    _Pragma("unroll") for (int ks = 0; ks < 4; ++ks) \
    _Pragma("unroll") for (int i = 0; i < 2; ++i) \
      acc[(sel) * 2 + i][bn] = __builtin_amdgcn_mfma_f32_32x32x16_bf16( \
          aS[i][ks], bS[ks], acc[(sel) * 2 + i][bn], 0, 0, 0); \
  } while (0)

#define PH_BAR do { __builtin_amdgcn_s_barrier(); asm volatile("" ::: "memory"); } while (0)
#define LGKM4 asm volatile("s_waitcnt lgkmcnt(4)" ::: "memory")
#define LGKM8 asm volatile("s_waitcnt lgkmcnt(8)" ::: "memory")
#define VMC2  asm volatile("s_waitcnt vmcnt(2)" ::: "memory")
#define VMC6  asm volatile("s_waitcnt vmcnt(6)" ::: "memory")
#define PRIO1 __builtin_amdgcn_s_setprio(1)
#define PRIO0 __builtin_amdgcn_s_setprio(0)

  // Prologue: buf0(k0) full (8 loads) + buf1(k1) 3 half-tiles (6 loads).
  STAGE_B(0, 0, 0); STAGE_B(0, 1, 0);
  STAGE_A(0, 0, 0); STAGE_A(0, 1, 0);
  STAGE_B(1, 0, 1); STAGE_B(1, 1, 1);
  STAGE_A(1, 0, 1);
  VMC6;        // buf0 complete; buf1's 6 loads stay in flight
  PH_BAR;
  LDA_SET(aS0, 0, 0);                      // "ph6" issue: 8 reads
  LDB_SET(bS0, 0, 0); LDB_SET(bS1, 0, 1);  // "ph7" issue: 8 reads

  // Steady state read-issue: reads for phase p issue at p-2; counted lgkm waits
  // target reads issued 2 phases ago. Stages shifted 1 phase early; vmcnt(2)
  // drains at ph1/ph5 (one full phase after last stage of the drained buffer).
  for (int t = 0; t < NKT / 2; ++t) {
    const int k1 = 2 * t + 1;
    const int k2 = (2 * t + 2 < NKT) ? 2 * t + 2 : NKT - 1;  // tail clamp (never read)
    const int k3 = (2 * t + 3 < NKT) ? 2 * t + 3 : NKT - 1;

    // ph0: Q(A0,B0)@buf0 ; issue aS1-half0(buf0)
    LDA_HALF(aS1, 0, 1, 0);
    STAGE_A(1, 1, k1);
    LGKM4;                       // completes ph6/ph7-issued: aS0,bS0,bS1(buf0)
    PRIO1; MMQ(aS0, bS0, 0, 0); PRIO0;
    PH_BAR;
    // ph1: Q(A0,B1) ; issue aS1-half1(buf0) ; drain buf1(k1) staging
    LDA_HALF(aS1, 0, 1, 1);
    STAGE_B(0, 0, k2);
    PRIO1; MMQ(aS0, bS1, 0, 1); PRIO0;
    VMC2;                        // buf1(k1) fully visible (leaves ph1's own stage)
    PH_BAR;
    // ph2: Q(A1,B1) ; issue aS0(buf1)
    LDA_SET(aS0, 1, 0);
    STAGE_B(0, 1, k2);
    LGKM8;                       // completes aS1 halves (ph0,ph1)
    PRIO1; MMQ(aS1, bS1, 1, 1); PRIO0;
    PH_BAR;
    // ph3: Q(A1,B0) FIRST (bS0/bS1 regs overwritten by this phase's issue)
    PRIO1; MMQ(aS1, bS0, 1, 0); PRIO0;
    LDB_SET(bS0, 1, 0); LDB_SET(bS1, 1, 1);
    STAGE_A(0, 0, k2);
    PH_BAR;
    // ph4: Q(A0,B0)@buf1 ; issue aS1-half0(buf1)
    LDA_HALF(aS1, 1, 1, 0);
    STAGE_A(0, 1, k2);
    LGKM4;                       // completes ph2(aS0)+ph3(bS0,bS1)
    PRIO1; MMQ(aS0, bS0, 0, 0); PRIO0;
    PH_BAR;
    // ph5: Q(A0,B1) ; issue aS1-half1(buf1) ; drain buf0(k2) staging
    LDA_HALF(aS1, 1, 1, 1);
    STAGE_B(1, 0, k3);
    PRIO1; MMQ(aS0, bS1, 0, 1); PRIO0;
    VMC2;                        // buf0(k2) fully visible
    PH_BAR;
    // ph6: Q(A1,B1) ; issue aS0(buf0,k2)
    LDA_SET(aS0, 0, 0);
    STAGE_B(1, 1, k3);
    LGKM8;                       // completes aS1(buf1) halves (ph4,ph5)
    PRIO1; MMQ(aS1, bS1, 1, 1); PRIO0;
    PH_BAR;
    // ph7: Q(A1,B0) FIRST, then issue bS0,bS1(buf0,k2)
    PRIO1; MMQ(aS1, bS0, 1, 0); PRIO0;
    LDB_SET(bS0, 0, 0); LDB_SET(bS1, 0, 1);
    STAGE_A(1, 0, k3);
    PH_BAR;
  }

  // ---- epilogue: y = acc*scale + bias ----
  // 32x32 C/D (m74/m101): col = lane&31, row = (reg&3) + 8*(reg>>2) + 4*(lane>>5)
  const int m0 = tm * 256, n0 = tn * 256;
#pragma unroll
  for (int ni = 0; ni < 2; ++ni) {
    const int o = n0 + wc * 64 + ni * 32 + l31;
    const float s = scales[o];
    const float b = bias[o];
#pragma unroll
    for (int mi = 0; mi < 4; ++mi) {
      const int mrb = m0 + wr * 128 + mi * 32 + kg * 4;
#pragma unroll
      for (int r = 0; r < 16; ++r) {
        const int mr = mrb + (r & 3) + 8 * (r >> 2);
        __builtin_nontemporal_store(acc[mi][ni][r] * s + b,
                                    out + (size_t)mr * N_DIM + o);
      }
    }
  }
#undef STAGE
#undef STAGE_A
#undef STAGE_B
#undef LDA_SET
#undef LDA_HALF
#undef LDB_SET
#undef MMQ
#undef PH_BAR
#undef LGKM4
#undef LGKM8
#undef VMC2
#undef VMC6
#undef PRIO1
#undef PRIO0
}

// ---------------- fallback pre-pass (linear xb) + 128x128 GEMM ----------------
__global__ __launch_bounds__(256) void cvt_x_kernel(const float* __restrict__ x,
                                                    unsigned short* __restrict__ xb) {
  const int n4 = M_DIM * K_DIM / 4;
  int i = blockIdx.x * blockDim.x + threadIdx.x;
  const int stride = gridDim.x * blockDim.x;
  for (; i < n4; i += stride) {
    float4 v = ((const float4*)x)[i];
    ushort4 r;
    r.x = f2bf_rne(v.x); r.y = f2bf_rne(v.y);
    r.z = f2bf_rne(v.z); r.w = f2bf_rne(v.w);
    ((ushort4*)xb)[i] = r;
  }
}

template <int MODE>
__global__ __launch_bounds__(256)
void qgemm_kernel(const float* __restrict__ x, const unsigned short* __restrict__ xb,
                  const int* __restrict__ wp,
                  const float* __restrict__ scales, const float* __restrict__ bias,
                  float* __restrict__ out) {
  __shared__ __align__(16) unsigned short As[BM * BK];
  __shared__ __align__(16) unsigned short Bs[BN * BK];
  const int tid  = threadIdx.x;
  const int lane = tid & 63;
  const int wid  = tid >> 6;
  int bid = blockIdx.x;
  int swzb = (bid & 7) * (NBLK / 8) + (bid >> 3);
  const int tm = swzb & (NTM - 1);
  const int tn = swzb >> 5;
  const int m0 = tm * BM, n0 = tn * BN;
  const int wr = wid >> 1, wc = wid & 1;
  const int fr = lane & 15;
  const int fg = lane >> 4;
  f32x4 acc[4][4] = {};

  for (int kt = 0; kt < K_DIM / BK; ++kt) {
    int4   breg[4];
    float4 areg[8];
#pragma unroll
    for (int p = 0; p < 4; ++p) {
      int fl = p * 256 + tid;
      int row = fl >> 3, u = fl & 7;
      breg[p] = *(const int4*)(wp + (size_t)(n0 + row) * KP + kt * (BK / 2) + u * 4);
    }
    if constexpr (MODE == 2) {
#pragma unroll
      for (int p = 0; p < 8; ++p) {
        int fl = p * 256 + tid;
        int row = fl >> 4, u = fl & 15;
        areg[p] = *(const float4*)(x + (size_t)(m0 + row) * K_DIM + kt * BK + u * 4);
      }
    }
    __syncthreads();
    if constexpr (MODE == 1) {
#pragma unroll
      for (int p = 0; p < 4; ++p) {
        int t16 = p * 256 + tid;
        int row = t16 >> 3, u = t16 & 7;
        const unsigned short* g = xb + (size_t)(m0 + row) * K_DIM + kt * BK + u * 8;
        async_copy16((char*)As + (p * 256 + wid * 64) * 16, g);
      }
    } else {
#pragma unroll
      for (int p = 0; p < 8; ++p) {
        int fl = p * 256 + tid;
        int row = fl >> 4, u = fl & 15;
        ushort4 r;
        r.x = f2bf_rne(areg[p].x); r.y = f2bf_rne(areg[p].y);
        r.z = f2bf_rne(areg[p].z); r.w = f2bf_rne(areg[p].w);
        *(ushort4*)((char*)As + row * 128 + u * 8) = r;
      }
    }
#pragma unroll
    for (int p = 0; p < 4; ++p) {
      int fl = p * 256 + tid;
      int row = fl >> 3, u = fl & 7;
      int4 b = breg[p];
      u16x8 r;
      r[0] = i2bf(sx4(b.x, 0)); r[1] = i2bf(sx4(b.x, 1));
      r[2] = i2bf(sx4(b.y, 0)); r[3] = i2bf(sx4(b.y, 1));
      r[4] = i2bf(sx4(b.z, 0)); r[5] = i2bf(sx4(b.z, 1));
      r[6] = i2bf(sx4(b.w, 0)); r[7] = i2bf(sx4(b.w, 1));
      *(u16x8*)((char*)Bs + row * 128 + u * 16) = r;
    }
    __syncthreads();
#pragma unroll
    for (int kk = 0; kk < 2; ++kk) {
      const int kb = kk * 64 + fg * 16;
      bf16x8 af[4], bfv[4];
#pragma unroll
      for (int mi = 0; mi < 4; ++mi) {
        int row = wr * 64 + mi * 16 + fr;
        af[mi] = *(const bf16x8*)((const char*)As + row * 128 + kb);
      }
#pragma unroll
      for (int ni = 0; ni < 4; ++ni) {
        int row = wc * 64 + ni * 16 + fr;
        bfv[ni] = *(const bf16x8*)((const char*)Bs + row * 128 + kb);
      }
#pragma unroll
      for (int mi = 0; mi < 4; ++mi)
#pragma unroll
        for (int ni = 0; ni < 4; ++ni)
          acc[mi][ni] = __builtin_amdgcn_mfma_f32_16x16x32_bf16(af[mi], bfv[ni], acc[mi][ni], 0, 0, 0);
    }
  }
#pragma unroll
  for (int ni = 0; ni < 4; ++ni) {
    const int o = n0 + wc * 64 + ni * 16 + fr;
    const float s = scales[o];
    const float b = bias[o];
#pragma unroll
    for (int mi = 0; mi < 4; ++mi) {
      const int mr = m0 + wr * 64 + mi * 16 + fg * 4;
#pragma unroll
      for (int r = 0; r < 4; ++r)
        out[(size_t)(mr + r) * N_DIM + o] = acc[mi][ni][r] * s + b;
    }
  }
}

extern "C" void kernel_launch(void* const* d_in, const int* in_sizes, int n_in,
                              void* d_out, int out_size, void* d_ws, size_t ws_size,
                              hipStream_t stream) {
  const float* x  = (const float*)d_in[0];
  const int*   wp = (const int*)d_in[1];
  const float* sc = (const float*)d_in[2];
  const float* bs = (const float*)d_in[3];
  float* out = (float*)d_out;

  const size_t a_bytes = (size_t)NTM2 * NKT * 2 * HT_BYTES;  // 33,554,432
  const size_t b_bytes = (size_t)NTN2 * NKT * 2 * HT_BYTES;  // 90,177,536
  unsigned short* wsA = (unsigned short*)d_ws;
  unsigned short* wsB = (unsigned short*)((char*)d_ws + a_bytes);

  if (ws_size >= a_bytes + b_bytes) {
    cvt_x_tiled<<<2048, 256, 0, stream>>>(x, wsA);
    deq_w_tiled<<<2048, 256, 0, stream>>>(wp, wsB);
    qgemm8<<<NBLK2, 512, 0, stream>>>(wsA, wsB, sc, bs, out);
  } else if (ws_size >= a_bytes) {
    cvt_x_kernel<<<2048, 256, 0, stream>>>(x, wsA);
    qgemm_kernel<1><<<NBLK, 256, 0, stream>>>(x, wsA, wp, sc, bs, out);
  } else {
    qgemm_kernel<2><<<NBLK, 256, 0, stream>>>(x, wsA, wp, sc, bs, out);
  }
}

// Round 9
// 378.557 us; speedup vs baseline: 1.0996x; 1.0996x over previous
//
#include <hip/hip_runtime.h>
#include <hip/hip_bf16.h>
#include <stdint.h>

// Problem dims
#define M_DIM 4096      // 2*2048 rows of x
#define K_DIM 4096
#define N_DIM 11008
#define KP    2048      // K/2 packed int32 per w row

// ---------------- 8-phase 256x256 GEMM geometry (BK=64) ----------------
#define BK2   64
#define NKT   (K_DIM/BK2)        // 64 K-tiles
#define NTM2  (M_DIM/256)        // 16
#define NTN2  (N_DIM/256)        // 43
#define NBLK2 (NTM2*NTN2)        // 688  (%8==0 -> bijective XCD swizzle)
#define HT_BYTES 16384           // half-tile: 128 rows x 64 bf16 (fragment-major)

// ---------------- 128x128 fallback geometry ----------------
#define BM 128
#define BN 128
#define BK 64
#define NTM (M_DIM/BM)
#define NTN (N_DIM/BN)
#define NBLK (NTM*NTN)

typedef __attribute__((ext_vector_type(8)))  short bf16x8;
typedef __attribute__((ext_vector_type(4)))  float f32x4;
typedef __attribute__((ext_vector_type(16))) float f32x16;
typedef __attribute__((ext_vector_type(8)))  unsigned short u16x8;

typedef const void __attribute__((address_space(1)))* gas_ptr;
typedef void __attribute__((address_space(3)))* las_ptr;

__device__ __forceinline__ void async_copy16(void* lds, const void* g) {
  __builtin_amdgcn_global_load_lds((gas_ptr)g, (las_ptr)lds, 16, 0, 0);
}

__device__ __forceinline__ unsigned short f2bf_rne(float f) {
  uint32_t u = __builtin_bit_cast(uint32_t, f);
  u += 0x7FFFu + ((u >> 16) & 1u);
  return (unsigned short)(u >> 16);
}
__device__ __forceinline__ unsigned short i2bf(int v) {
  float f = (float)v;
  return (unsigned short)(__builtin_bit_cast(uint32_t, f) >> 16);
}
__device__ __forceinline__ int sx4(int b, int which) {
  return ((int)((uint32_t)b << (28 - 4 * which))) >> 28;
}

// ---------------- pre-pass: fragment-major half-tile images (R6-proven) ----------
// Half-tile image (16KB = 1024 x 16B chunks): chunk c = msub*256 + ks*64 + kg*32 + l31
// holds T[msub*32 + l31][ks*16 + kg*8 .. +8]  (T = 128-row x 64-col bf16 tile).
// A wave's MFMA fragment read (fixed msub,ks) = 64 lanes x 16B CONTIGUOUS -> 0 conflicts.

__global__ __launch_bounds__(256) void cvt_x_tiled(const float* __restrict__ x,
                                                   unsigned short* __restrict__ wsA) {
  const int total = NTM2 * NKT * 2 * 1024;   // 16B chunks, source-ordered
  for (int i = blockIdx.x * blockDim.x + threadIdx.x; i < total;
       i += gridDim.x * blockDim.x) {
    int rc  = i & 1023;            // source chunk within half-tile
    int h   = (i >> 10) & 1;
    int kt  = (i >> 11) & 63;
    int tm  = i >> 17;
    int row = rc >> 3, e8 = rc & 7;          // 8 consecutive f32 per chunk (coalesced)
    const float* src = x + (size_t)(tm * 256 + h * 128 + row) * K_DIM + kt * 64 + e8 * 8;
    float4 v0 = *(const float4*)src;
    float4 v1 = *(const float4*)(src + 4);
    u16x8 r;
    r[0] = f2bf_rne(v0.x); r[1] = f2bf_rne(v0.y); r[2] = f2bf_rne(v0.z); r[3] = f2bf_rne(v0.w);
    r[4] = f2bf_rne(v1.x); r[5] = f2bf_rne(v1.y); r[6] = f2bf_rne(v1.z); r[7] = f2bf_rne(v1.w);
    int c = (row >> 5) * 256 + (e8 >> 1) * 64 + (e8 & 1) * 32 + (row & 31);
    *(u16x8*)((char*)wsA + (size_t)(i >> 10) * HT_BYTES + c * 16) = r;
  }
}

__global__ __launch_bounds__(256) void deq_w_tiled(const int* __restrict__ wp,
                                                   unsigned short* __restrict__ wsB) {
  const int total = NTN2 * NKT * 2 * 1024;
  for (int i = blockIdx.x * blockDim.x + threadIdx.x; i < total;
       i += gridDim.x * blockDim.x) {
    int rc  = i & 1023;
    int h   = (i >> 10) & 1;
    int kt  = (i >> 11) & 63;
    int tn  = i >> 17;
    int row = rc >> 3, e8 = rc & 7;
    int4 b = *(const int4*)(wp + (size_t)(tn * 256 + h * 128 + row) * KP + kt * 32 + e8 * 4);
    u16x8 r;
    r[0] = i2bf(sx4(b.x, 0)); r[1] = i2bf(sx4(b.x, 1));
    r[2] = i2bf(sx4(b.y, 0)); r[3] = i2bf(sx4(b.y, 1));
    r[4] = i2bf(sx4(b.z, 0)); r[5] = i2bf(sx4(b.z, 1));
    r[6] = i2bf(sx4(b.w, 0)); r[7] = i2bf(sx4(b.w, 1));
    int c = (row >> 5) * 256 + (e8 >> 1) * 64 + (e8 & 1) * 32 + (row & 31);
    *(u16x8*)((char*)wsB + (size_t)(i >> 10) * HT_BYTES + c * 16) = r;
  }
}

// ------- 8-phase 256x256 GEMM, 32x32x16, m201-style two-barrier phases -------
__global__ __launch_bounds__(512, 2)
void qgemm8(const unsigned short* __restrict__ wsA, const unsigned short* __restrict__ wsB,
            const float* __restrict__ scales, const float* __restrict__ bias,
            float* __restrict__ out) {
  __shared__ __align__(16) char smem[131072];  // 2 buf x (A 32KB + B 32KB)

  const int tid  = threadIdx.x;
  const int lane = tid & 63, wid = tid >> 6;
  const int wr = wid >> 2, wc = wid & 3;       // 2x4 wave grid; per-wave 128x64
  const int l31 = lane & 31, kg = lane >> 5;

  int bid = blockIdx.x;
  int id  = (bid & 7) * (NBLK2 / 8) + (bid >> 3);   // bijective XCD chunking
  int tm  = id & (NTM2 - 1), tn = id >> 4;          // tn-major: B panel shared per XCD

  const char* gA = (const char*)wsA + (size_t)tm * (NKT * 2) * HT_BYTES;
  const char* gB = (const char*)wsB + (size_t)tn * (NKT * 2) * HT_BYTES;

  // Per-lane fragment bases: read group = 64 lanes x 16B contiguous (conflict-free)
  const char* baseA = smem + wr * HT_BYTES + lane * 16;
  const char* baseB = smem + 32768 + (wc >> 1) * HT_BYTES + lane * 16;

#define STAGE(ldsoff, src) do { \
    async_copy16(smem + (ldsoff) + (wid * 64) * 16, (src) + (wid * 64 + lane) * 16); \
    async_copy16(smem + (ldsoff) + (512 + wid * 64) * 16, (src) + (512 + wid * 64 + lane) * 16); \
  } while (0)
#define STAGE_A(buf, h, kt) STAGE((buf) * 65536 + (h) * HT_BYTES, gA + ((kt) * 2 + (h)) * HT_BYTES)
#define STAGE_B(buf, h, kt) STAGE((buf) * 65536 + 32768 + (h) * HT_BYTES, gB + ((kt) * 2 + (h)) * HT_BYTES)

  f32x16 acc[4][2] = {};   // [msub 0..3][nsub 0..1], 128 regs (AGPR side)
  bf16x8 aS0[2][4], aS1[2][4];   // A frag sets: [msub-in-pair][kstep]
  bf16x8 bS0[4], bS1[4];         // B frag sets: [kstep]

#define LDA_SET(dst, buf, sel) do { \
    _Pragma("unroll") for (int i = 0; i < 2; ++i) \
    _Pragma("unroll") for (int ks = 0; ks < 4; ++ks) \
      dst[i][ks] = *(const bf16x8*)(baseA + (buf) * 65536 + ((sel) * 2 + i) * 4096 + ks * 1024); \
  } while (0)
#define LDB_SET(dst, buf, bn) do { \
    _Pragma("unroll") for (int ks = 0; ks < 4; ++ks) \
      dst[ks] = *(const bf16x8*)(baseB + (buf) * 65536 + ((wc & 1) * 2 + (bn)) * 4096 + ks * 1024); \
  } while (0)
#define MMQ(aS, bS, sel, bn) do { \
    _Pragma("unroll") for (int ks = 0; ks < 4; ++ks) \
    _Pragma("unroll") for (int i = 0; i < 2; ++i) \
      acc[(sel) * 2 + i][bn] = __builtin_amdgcn_mfma_f32_32x32x16_bf16( \
          aS[i][ks], bS[ks], acc[(sel) * 2 + i][bn], 0, 0, 0); \
  } while (0)

#define PH_BAR __builtin_amdgcn_s_barrier()
#define LGKM0 asm volatile("s_waitcnt lgkmcnt(0)" ::: "memory")
#define VMC4  asm volatile("s_waitcnt vmcnt(4)" ::: "memory")
#define PRIO1 __builtin_amdgcn_s_setprio(1)
#define PRIO0 __builtin_amdgcn_s_setprio(0)

  // Prologue: buf0 <- tile0 (8 loads), buf1.B <- tile1 (4 loads). 12 total.
  STAGE_B(0, 0, 0); STAGE_B(0, 1, 0);
  STAGE_A(0, 0, 0); STAGE_A(0, 1, 0);
  STAGE_B(1, 0, 1); STAGE_B(1, 1, 1);
  VMC4;        // drain buf0's 8, keep buf1.B's 4 in flight
  PH_BAR;

  // m201 skeleton: per phase {ds-loads for THIS phase; stage; BAR; lgkm0;
  // prio1; MFMA quadrant; prio0; BAR}. Counted vmcnt(4) only at ph3/ph7:
  // drains the 8 oldest loads (= the buffer the next 4 phases read), keeps 4.
  for (int t = 0; t < NKT / 2; ++t) {
    const int k1 = 2 * t + 1;
    const int k2 = (2 * t + 2 < NKT) ? 2 * t + 2 : NKT - 1;  // tail clamp (never read)
    const int k3 = (2 * t + 3 < NKT) ? 2 * t + 3 : NKT - 1;

    // ph0: Q(A0,B0)@buf0
    LDA_SET(aS0, 0, 0); LDB_SET(bS0, 0, 0);
    STAGE_A(1, 0, k1);
    PH_BAR; LGKM0;
    PRIO1; MMQ(aS0, bS0, 0, 0); PRIO0;
    PH_BAR;
    // ph1: Q(A0,B1)@buf0
    LDB_SET(bS1, 0, 1);
    STAGE_A(1, 1, k1);
    PH_BAR; LGKM0;
    PRIO1; MMQ(aS0, bS1, 0, 1); PRIO0;
    PH_BAR;
    // ph2: Q(A1,B1)@buf0
    LDA_SET(aS1, 0, 1);
    STAGE_B(0, 0, k2);
    PH_BAR; LGKM0;
    PRIO1; MMQ(aS1, bS1, 1, 1); PRIO0;
    PH_BAR;
    // ph3: Q(A1,B0)@buf0 (regs); drain buf1(k1) before ph4 reads it
    STAGE_B(0, 1, k2);
    VMC4;
    PH_BAR;
    PRIO1; MMQ(aS1, bS0, 1, 0); PRIO0;
    PH_BAR;
    // ph4: Q(A0,B0)@buf1
    LDA_SET(aS0, 1, 0); LDB_SET(bS0, 1, 0);
    STAGE_A(0, 0, k2);
    PH_BAR; LGKM0;
    PRIO1; MMQ(aS0, bS0, 0, 0); PRIO0;
    PH_BAR;
    // ph5: Q(A0,B1)@buf1
    LDB_SET(bS1, 1, 1);
    STAGE_A(0, 1, k2);
    PH_BAR; LGKM0;
    PRIO1; MMQ(aS0, bS1, 0, 1); PRIO0;
    PH_BAR;
    // ph6: Q(A1,B1)@buf1
    LDA_SET(aS1, 1, 1);
    STAGE_B(1, 0, k3);
    PH_BAR; LGKM0;
    PRIO1; MMQ(aS1, bS1, 1, 1); PRIO0;
    PH_BAR;
    // ph7: Q(A1,B0)@buf1 (regs); drain buf0(k2) before next ph0 reads it
    STAGE_B(1, 1, k3);
    VMC4;
    PH_BAR;
    PRIO1; MMQ(aS1, bS0, 1, 0); PRIO0;
    PH_BAR;
  }

  // ---- epilogue: y = acc*scale + bias ----
  // 32x32 C/D (m74/m101): col = lane&31, row = (reg&3) + 8*(reg>>2) + 4*(lane>>5)
  const int m0 = tm * 256, n0 = tn * 256;
#pragma unroll
  for (int ni = 0; ni < 2; ++ni) {
    const int o = n0 + wc * 64 + ni * 32 + l31;
    const float s = scales[o];
    const float b = bias[o];
#pragma unroll
    for (int mi = 0; mi < 4; ++mi) {
      const int mrb = m0 + wr * 128 + mi * 32 + kg * 4;
#pragma unroll
      for (int r = 0; r < 16; ++r) {
        const int mr = mrb + (r & 3) + 8 * (r >> 2);
        __builtin_nontemporal_store(acc[mi][ni][r] * s + b,
                                    out + (size_t)mr * N_DIM + o);
      }
    }
  }
#undef STAGE
#undef STAGE_A
#undef STAGE_B
#undef LDA_SET
#undef LDB_SET
#undef MMQ
#undef PH_BAR
#undef LGKM0
#undef VMC4
#undef PRIO1
#undef PRIO0
}

// ---------------- fallback pre-pass (linear xb) + 128x128 GEMM ----------------
__global__ __launch_bounds__(256) void cvt_x_kernel(const float* __restrict__ x,
                                                    unsigned short* __restrict__ xb) {
  const int n4 = M_DIM * K_DIM / 4;
  int i = blockIdx.x * blockDim.x + threadIdx.x;
  const int stride = gridDim.x * blockDim.x;
  for (; i < n4; i += stride) {
    float4 v = ((const float4*)x)[i];
    ushort4 r;
    r.x = f2bf_rne(v.x); r.y = f2bf_rne(v.y);
    r.z = f2bf_rne(v.z); r.w = f2bf_rne(v.w);
    ((ushort4*)xb)[i] = r;
  }
}

template <int MODE>
__global__ __launch_bounds__(256)
void qgemm_kernel(const float* __restrict__ x, const unsigned short* __restrict__ xb,
                  const int* __restrict__ wp,
                  const float* __restrict__ scales, const float* __restrict__ bias,
                  float* __restrict__ out) {
  __shared__ __align__(16) unsigned short As[BM * BK];
  __shared__ __align__(16) unsigned short Bs[BN * BK];
  const int tid  = threadIdx.x;
  const int lane = tid & 63;
  const int wid  = tid >> 6;
  int bid = blockIdx.x;
  int swzb = (bid & 7) * (NBLK / 8) + (bid >> 3);
  const int tm = swzb & (NTM - 1);
  const int tn = swzb >> 5;
  const int m0 = tm * BM, n0 = tn * BN;
  const int wr = wid >> 1, wc = wid & 1;
  const int fr = lane & 15;
  const int fg = lane >> 4;
  f32x4 acc[4][4] = {};

  for (int kt = 0; kt < K_DIM / BK; ++kt) {
    int4   breg[4];
    float4 areg[8];
#pragma unroll
    for (int p = 0; p < 4; ++p) {
      int fl = p * 256 + tid;
      int row = fl >> 3, u = fl & 7;
      breg[p] = *(const int4*)(wp + (size_t)(n0 + row) * KP + kt * (BK / 2) + u * 4);
    }
    if constexpr (MODE == 2) {
#pragma unroll
      for (int p = 0; p < 8; ++p) {
        int fl = p * 256 + tid;
        int row = fl >> 4, u = fl & 15;
        areg[p] = *(const float4*)(x + (size_t)(m0 + row) * K_DIM + kt * BK + u * 4);
      }
    }
    __syncthreads();
    if constexpr (MODE == 1) {
#pragma unroll
      for (int p = 0; p < 4; ++p) {
        int t16 = p * 256 + tid;
        int row = t16 >> 3, u = t16 & 7;
        const unsigned short* g = xb + (size_t)(m0 + row) * K_DIM + kt * BK + u * 8;
        async_copy16((char*)As + (p * 256 + wid * 64) * 16, g);
      }
    } else {
#pragma unroll
      for (int p = 0; p < 8; ++p) {
        int fl = p * 256 + tid;
        int row = fl >> 4, u = fl & 15;
        ushort4 r;
        r.x = f2bf_rne(areg[p].x); r.y = f2bf_rne(areg[p].y);
        r.z = f2bf_rne(areg[p].z); r.w = f2bf_rne(areg[p].w);
        *(ushort4*)((char*)As + row * 128 + u * 8) = r;
      }
    }
#pragma unroll
    for (int p = 0; p < 4; ++p) {
      int fl = p * 256 + tid;
      int row = fl >> 3, u = fl & 7;
      int4 b = breg[p];
      u16x8 r;
      r[0] = i2bf(sx4(b.x, 0)); r[1] = i2bf(sx4(b.x, 1));
      r[2] = i2bf(sx4(b.y, 0)); r[3] = i2bf(sx4(b.y, 1));
      r[4] = i2bf(sx4(b.z, 0)); r[5] = i2bf(sx4(b.z, 1));
      r[6] = i2bf(sx4(b.w, 0)); r[7] = i2bf(sx4(b.w, 1));
      *(u16x8*)((char*)Bs + row * 128 + u * 16) = r;
    }
    __syncthreads();
#pragma unroll
    for (int kk = 0; kk < 2; ++kk) {
      const int kb = kk * 64 + fg * 16;
      bf16x8 af[4], bfv[4];
#pragma unroll
      for (int mi = 0; mi < 4; ++mi) {
        int row = wr * 64 + mi * 16 + fr;
        af[mi] = *(const bf16x8*)((const char*)As + row * 128 + kb);
      }
#pragma unroll
      for (int ni = 0; ni < 4; ++ni) {
        int row = wc * 64 + ni * 16 + fr;
        bfv[ni] = *(const bf16x8*)((const char*)Bs + row * 128 + kb);
      }
#pragma unroll
      for (int mi = 0; mi < 4; ++mi)
#pragma unroll
        for (int ni = 0; ni < 4; ++ni)
          acc[mi][ni] = __builtin_amdgcn_mfma_f32_16x16x32_bf16(af[mi], bfv[ni], acc[mi][ni], 0, 0, 0);
    }
  }
#pragma unroll
  for (int ni = 0; ni < 4; ++ni) {
    const int o = n0 + wc * 64 + ni * 16 + fr;
    const float s = scales[o];
    const float b = bias[o];
#pragma unroll
    for (int mi = 0; mi < 4; ++mi) {
      const int mr = m0 + wr * 64 + mi * 16 + fg * 4;
#pragma unroll
      for (int r = 0; r < 4; ++r)
        out[(size_t)(mr + r) * N_DIM + o] = acc[mi][ni][r] * s + b;
    }
  }
}

extern "C" void kernel_launch(void* const* d_in, const int* in_sizes, int n_in,
                              void* d_out, int out_size, void* d_ws, size_t ws_size,
                              hipStream_t stream) {
  const float* x  = (const float*)d_in[0];
  const int*   wp = (const int*)d_in[1];
  const float* sc = (const float*)d_in[2];
  const float* bs = (const float*)d_in[3];
  float* out = (float*)d_out;

  const size_t a_bytes = (size_t)NTM2 * NKT * 2 * HT_BYTES;  // 33,554,432
  const size_t b_bytes = (size_t)NTN2 * NKT * 2 * HT_BYTES;  // 90,177,536
  unsigned short* wsA = (unsigned short*)d_ws;
  unsigned short* wsB = (unsigned short*)((char*)d_ws + a_bytes);

  if (ws_size >= a_bytes + b_bytes) {
    cvt_x_tiled<<<2048, 256, 0, stream>>>(x, wsA);
    deq_w_tiled<<<2048, 256, 0, stream>>>(wp, wsB);
    qgemm8<<<NBLK2, 512, 0, stream>>>(wsA, wsB, sc, bs, out);
  } else if (ws_size >= a_bytes) {
    cvt_x_kernel<<<2048, 256, 0, stream>>>(x, wsA);
    qgemm_kernel<1><<<NBLK, 256, 0, stream>>>(x, wsA, wp, sc, bs, out);
  } else {
    qgemm_kernel<2><<<NBLK, 256, 0, stream>>>(x, wsA, wp, sc, bs, out);
  }
}

// Round 10
// 265.192 us; speedup vs baseline: 1.5696x; 1.4275x over previous
//
#include <hip/hip_runtime.h>
#include <hip/hip_bf16.h>
#include <stdint.h>

// Problem dims
#define M_DIM 4096      // 2*2048 rows of x
#define K_DIM 4096
#define N_DIM 11008
#define KP    2048      // K/2 packed int32 per w row

// ---------------- i8 8-phase 256x256 GEMM geometry (BK=64) ----------------
#define BK2   64
#define NKT   (K_DIM/BK2)        // 64 K-tiles
#define NTM2  (M_DIM/256)        // 16
#define NTN2  (N_DIM/256)        // 43
#define NBLK2 (NTM2*NTN2)        // 688  (%8==0 -> bijective XCD swizzle)
#define HT_BYTES 8192            // half-tile: 128 rows x 64 i8 (fragment-major)

// ---------------- 128x128 bf16 fallback geometry ----------------
#define BM 128
#define BN 128
#define BK 64
#define NTM (M_DIM/BM)
#define NTN (N_DIM/BN)
#define NBLK (NTM*NTN)

typedef __attribute__((ext_vector_type(8)))  short bf16x8;
typedef __attribute__((ext_vector_type(4)))  float f32x4;
typedef __attribute__((ext_vector_type(4)))  int   i32x4;
typedef __attribute__((ext_vector_type(16))) int   i32x16;
typedef __attribute__((ext_vector_type(16))) char  c8x16;
typedef __attribute__((ext_vector_type(8)))  unsigned short u16x8;

typedef const void __attribute__((address_space(1)))* gas_ptr;
typedef void __attribute__((address_space(3)))* las_ptr;

__device__ __forceinline__ void async_copy16(void* lds, const void* g) {
  __builtin_amdgcn_global_load_lds((gas_ptr)g, (las_ptr)lds, 16, 0, 0);
}

__device__ __forceinline__ unsigned short f2bf_rne(float f) {
  uint32_t u = __builtin_bit_cast(uint32_t, f);
  u += 0x7FFFu + ((u >> 16) & 1u);
  return (unsigned short)(u >> 16);
}
__device__ __forceinline__ unsigned short i2bf(int v) {
  float f = (float)v;
  return (unsigned short)(__builtin_bit_cast(uint32_t, f) >> 16);
}
__device__ __forceinline__ int sx4(int b, int which) {
  return ((int)((uint32_t)b << (28 - 4 * which))) >> 28;
}

// ---------------- i8 pre-pass ----------------
// Fragment-major half-tile image (8KB = 512 x 16B chunks):
// chunk c = sub*128 + ks*64 + kg*32 + l31 holds T[sub*32 + l31][ks*32 + kg*16 .. +16]
// (T = 128-row x 64-col i8 tile). MFMA frag read (fixed sub,ks) = 64 lanes x 16B
// contiguous -> 0 bank conflicts. Per-lane k-slice: kg*16 + [0..16) (K/2-consecutive,
// by verified bf16 analogy).

// 1) per-row max|x| -> xs[row] = max/127 (dequant scale), xr[row] = 127/max (quant)
__global__ __launch_bounds__(256) void rowmax_x(const float* __restrict__ x,
                                                float* __restrict__ xs,
                                                float* __restrict__ xr) {
  const int row = blockIdx.x;
  const int tid = threadIdx.x;
  const float4* r4 = (const float4*)(x + (size_t)row * K_DIM);
  float m = 0.f;
  for (int j = tid; j < K_DIM / 4; j += 256) {
    float4 v = r4[j];
    m = fmaxf(m, fmaxf(fmaxf(fabsf(v.x), fabsf(v.y)), fmaxf(fabsf(v.z), fabsf(v.w))));
  }
  for (int off = 32; off >= 1; off >>= 1) m = fmaxf(m, __shfl_down(m, off));
  __shared__ float sm[4];
  if ((tid & 63) == 0) sm[tid >> 6] = m;
  __syncthreads();
  if (tid == 0) {
    m = fmaxf(fmaxf(sm[0], sm[1]), fmaxf(sm[2], sm[3]));
    xs[row] = m * (1.0f / 127.0f);
    xr[row] = (m > 0.f) ? 127.0f / m : 0.f;
  }
}

// 2) quantize + tile x -> i8 A image [tm][kt][h]
__global__ __launch_bounds__(256) void quant_x_tiled(const float* __restrict__ x,
                                                     const float* __restrict__ xr,
                                                     char* __restrict__ wsA) {
  const int total = NTM2 * NKT * 2 * 512;   // 16B chunks (16 i8 = 16 f32 source)
  for (int i = blockIdx.x * blockDim.x + threadIdx.x; i < total;
       i += gridDim.x * blockDim.x) {
    int rc  = i & 511;
    int h   = (i >> 9) & 1;
    int kt  = (i >> 10) & 63;
    int tm  = i >> 16;
    int row = rc >> 2, e = rc & 3;           // 4 chunks of 16 f32 per row
    int grow = tm * 256 + h * 128 + row;
    const float4* src = (const float4*)(x + (size_t)grow * K_DIM + kt * 64 + e * 16);
    float4 v0 = src[0], v1 = src[1], v2 = src[2], v3 = src[3];
    float vv[16] = { v0.x, v0.y, v0.z, v0.w, v1.x, v1.y, v1.z, v1.w,
                     v2.x, v2.y, v2.z, v2.w, v3.x, v3.y, v3.z, v3.w };
    const float rs = xr[grow];
    c8x16 q;
#pragma unroll
    for (int j = 0; j < 16; ++j) q[j] = (char)__float2int_rn(vv[j] * rs);
    int c = (row >> 5) * 128 + (e >> 1) * 64 + (e & 1) * 32 + (row & 31);
    *(c8x16*)(wsA + (size_t)(i >> 9) * HT_BYTES + c * 16) = q;
  }
}

// 3) unpack int4 -> i8 B image [tn][kt][h] (exact)
__global__ __launch_bounds__(256) void deq_w_i8(const int* __restrict__ wp,
                                                char* __restrict__ wsB) {
  const int total = NTN2 * NKT * 2 * 512;
  for (int i = blockIdx.x * blockDim.x + threadIdx.x; i < total;
       i += gridDim.x * blockDim.x) {
    int rc  = i & 511;
    int h   = (i >> 9) & 1;
    int kt  = (i >> 10) & 63;
    int tn  = i >> 16;
    int row = rc >> 2, e = rc & 3;
    const int4* src = (const int4*)(wp + (size_t)(tn * 256 + h * 128 + row) * KP + kt * 32 + e * 8);
    int4 a = src[0], b = src[1];
    c8x16 q;
    q[0]  = (char)sx4(a.x, 0); q[1]  = (char)sx4(a.x, 1);
    q[2]  = (char)sx4(a.y, 0); q[3]  = (char)sx4(a.y, 1);
    q[4]  = (char)sx4(a.z, 0); q[5]  = (char)sx4(a.z, 1);
    q[6]  = (char)sx4(a.w, 0); q[7]  = (char)sx4(a.w, 1);
    q[8]  = (char)sx4(b.x, 0); q[9]  = (char)sx4(b.x, 1);
    q[10] = (char)sx4(b.y, 0); q[11] = (char)sx4(b.y, 1);
    q[12] = (char)sx4(b.z, 0); q[13] = (char)sx4(b.z, 1);
    q[14] = (char)sx4(b.w, 0); q[15] = (char)sx4(b.w, 1);
    int c = (row >> 5) * 128 + (e >> 1) * 64 + (e & 1) * 32 + (row & 31);
    *(c8x16*)(wsB + (size_t)(i >> 9) * HT_BYTES + c * 16) = q;
  }
}

// ------- i8 8-phase 256x256 GEMM, 32x32x32_i8, R6-proven schedule -------
__global__ __launch_bounds__(512, 2)
void qgemm8i(const char* __restrict__ wsA, const char* __restrict__ wsB,
             const float* __restrict__ xs,
             const float* __restrict__ scales, const float* __restrict__ bias,
             float* __restrict__ out) {
  __shared__ __align__(16) char smem[65536];  // 2 buf x (A 16KB + B 16KB)

  const int tid  = threadIdx.x;
  const int lane = tid & 63, wid = tid >> 6;
  const int wr = wid >> 2, wc = wid & 3;       // 2x4 wave grid; per-wave 128x64
  const int l31 = lane & 31, kg = lane >> 5;

  int bid = blockIdx.x;
  int id  = (bid & 7) * (NBLK2 / 8) + (bid >> 3);   // bijective XCD chunking
  int tm  = id & (NTM2 - 1), tn = id >> 4;          // tn-major: B panel shared per XCD

  const char* gA = wsA + (size_t)tm * (NKT * 2) * HT_BYTES;
  const char* gB = wsB + (size_t)tn * (NKT * 2) * HT_BYTES;

  // buf layout: [buf][A h0 8KB | A h1 8KB | B h0 8KB | B h1 8KB]
  const char* baseA = smem + wr * HT_BYTES + lane * 16;
  const char* baseB = smem + 16384 + (wc >> 1) * HT_BYTES + lane * 16;

#define STAGE(ldsoff, src) \
    async_copy16(smem + (ldsoff) + wid * 1024, (src) + wid * 1024 + lane * 16)
#define STAGE_A(buf, h, kt) STAGE((buf) * 32768 + (h) * HT_BYTES, gA + ((kt) * 2 + (h)) * HT_BYTES)
#define STAGE_B(buf, h, kt) STAGE((buf) * 32768 + 16384 + (h) * HT_BYTES, gB + ((kt) * 2 + (h)) * HT_BYTES)

  i32x16 acc[4][2] = {};   // [msub 0..3][nsub 0..1], 128 regs
  i32x4  aS0[2][2], aS1[2][2];   // A frag sets: [msub-in-pair][ks]
  i32x4  bS0[2], bS1[2];         // B frag sets: [ks]

#define LDA_SET(dst, buf, sel) do { \
    _Pragma("unroll") for (int i = 0; i < 2; ++i) \
    _Pragma("unroll") for (int ks = 0; ks < 2; ++ks) \
      dst[i][ks] = *(const i32x4*)(baseA + (buf) * 32768 + ((sel) * 2 + i) * 2048 + ks * 1024); \
  } while (0)
#define LDB_SET(dst, buf, bn) do { \
    _Pragma("unroll") for (int ks = 0; ks < 2; ++ks) \
      dst[ks] = *(const i32x4*)(baseB + (buf) * 32768 + ((wc & 1) * 2 + (bn)) * 2048 + ks * 1024); \
  } while (0)
#define MMQ(aS, bS, sel, bn) do { \
    _Pragma("unroll") for (int ks = 0; ks < 2; ++ks) \
    _Pragma("unroll") for (int i = 0; i < 2; ++i) \
      acc[(sel) * 2 + i][bn] = __builtin_amdgcn_mfma_i32_32x32x32_i8( \
          aS[i][ks], bS[ks], acc[(sel) * 2 + i][bn], 0, 0, 0); \
  } while (0)

#define PH_BAR __builtin_amdgcn_s_barrier()
#define LGKM0 asm volatile("s_waitcnt lgkmcnt(0)" ::: "memory")
#define VMC1  asm volatile("s_waitcnt vmcnt(1)" ::: "memory")
#define VMC2  asm volatile("s_waitcnt vmcnt(2)" ::: "memory")
#define PRIO1 __builtin_amdgcn_s_setprio(1)
#define PRIO0 __builtin_amdgcn_s_setprio(0)

  // Prologue: buf0 <- tile0 (4 loads), buf1.B <- tile1 (2 loads).
  STAGE_B(0, 0, 0); STAGE_B(0, 1, 0);
  STAGE_A(0, 0, 0); STAGE_A(0, 1, 0);
  STAGE_B(1, 0, 1); STAGE_B(1, 1, 1);
  VMC2;        // drain buf0's 4, keep buf1.B's 2 in flight
  PH_BAR;
  LDA_SET(aS0, 0, 0); LDB_SET(bS0, 0, 0);   // operands for ph0

  for (int t = 0; t < NKT / 2; ++t) {
    const int k1 = 2 * t + 1;
    const int k2 = (2 * t + 2 < NKT) ? 2 * t + 2 : NKT - 1;  // tail clamp (never read)
    const int k3 = (2 * t + 3 < NKT) ? 2 * t + 3 : NKT - 1;

    // ph0: Q(A0,B0)@buf0 ; prefetch bS1
    LGKM0; PRIO1; MMQ(aS0, bS0, 0, 0); PRIO0;
    STAGE_A(1, 0, k1);
    LDB_SET(bS1, 0, 1);
    PH_BAR;
    // ph1: Q(A0,B1) ; prefetch aS1
    LGKM0; PRIO1; MMQ(aS0, bS1, 0, 1); PRIO0;
    STAGE_A(1, 1, k1);
    LDA_SET(aS1, 0, 1);
    PH_BAR;
    // ph2: Q(A1,B1) ; drain buf1(k1): keep only ph2's own stage
    LGKM0; PRIO1; MMQ(aS1, bS1, 1, 1); PRIO0;
    STAGE_B(0, 0, k2);
    VMC1;
    PH_BAR;
    // ph3: Q(A1,B0) ; prefetch buf1 operands (aS0, bS0)
    PRIO1; MMQ(aS1, bS0, 1, 0); PRIO0;
    STAGE_B(0, 1, k2);
    LDA_SET(aS0, 1, 0); LDB_SET(bS0, 1, 0);
    PH_BAR;
    // ph4: Q(A0,B0)@buf1
    LGKM0; PRIO1; MMQ(aS0, bS0, 0, 0); PRIO0;
    STAGE_A(0, 0, k2);
    LDB_SET(bS1, 1, 1);
    PH_BAR;
    // ph5: Q(A0,B1)
    LGKM0; PRIO1; MMQ(aS0, bS1, 0, 1); PRIO0;
    STAGE_A(0, 1, k2);
    LDA_SET(aS1, 1, 1);
    PH_BAR;
    // ph6: Q(A1,B1) ; drain buf0(k2): keep only ph6's own stage
    LGKM0; PRIO1; MMQ(aS1, bS1, 1, 1); PRIO0;
    STAGE_B(1, 0, k3);
    VMC1;
    PH_BAR;
    // ph7: Q(A1,B0) ; prefetch buf0 operands for next iter
    PRIO1; MMQ(aS1, bS0, 1, 0); PRIO0;
    STAGE_B(1, 1, k3);
    LDA_SET(aS0, 0, 0); LDB_SET(bS0, 0, 0);
    PH_BAR;
  }

  // ---- epilogue: y = acc_i32 * xs[m] * ws[o] + bias[o] ----
  // 32x32 C/D (shape-determined, dtype-independent): col = lane&31,
  // row = (reg&3) + 8*(reg>>2) + 4*(lane>>5)
  const int m0 = tm * 256, n0 = tn * 256;
#pragma unroll
  for (int ni = 0; ni < 2; ++ni) {
    const int o = n0 + wc * 64 + ni * 32 + l31;
    const float sw = scales[o];
    const float b = bias[o];
#pragma unroll
    for (int mi = 0; mi < 4; ++mi) {
      const int mrb = m0 + wr * 128 + mi * 32 + kg * 4;
#pragma unroll
      for (int r = 0; r < 16; ++r) {
        const int mr = mrb + (r & 3) + 8 * (r >> 2);
        const float y = (float)acc[mi][ni][r] * xs[mr] * sw + b;
        __builtin_nontemporal_store(y, out + (size_t)mr * N_DIM + o);
      }
    }
  }
#undef STAGE
#undef STAGE_A
#undef STAGE_B
#undef LDA_SET
#undef LDB_SET
#undef MMQ
#undef PH_BAR
#undef LGKM0
#undef VMC1
#undef VMC2
#undef PRIO1
#undef PRIO0
}

// ---------------- bf16 fallback: linear xb prepass + 128x128 GEMM ----------------
__global__ __launch_bounds__(256) void cvt_x_kernel(const float* __restrict__ x,
                                                    unsigned short* __restrict__ xb) {
  const int n4 = M_DIM * K_DIM / 4;
  int i = blockIdx.x * blockDim.x + threadIdx.x;
  const int stride = gridDim.x * blockDim.x;
  for (; i < n4; i += stride) {
    float4 v = ((const float4*)x)[i];
    ushort4 r;
    r.x = f2bf_rne(v.x); r.y = f2bf_rne(v.y);
    r.z = f2bf_rne(v.z); r.w = f2bf_rne(v.w);
    ((ushort4*)xb)[i] = r;
  }
}

template <int MODE>
__global__ __launch_bounds__(256)
void qgemm_kernel(const float* __restrict__ x, const unsigned short* __restrict__ xb,
                  const int* __restrict__ wp,
                  const float* __restrict__ scales, const float* __restrict__ bias,
                  float* __restrict__ out) {
  __shared__ __align__(16) unsigned short As[BM * BK];
  __shared__ __align__(16) unsigned short Bs[BN * BK];
  const int tid  = threadIdx.x;
  const int lane = tid & 63;
  const int wid  = tid >> 6;
  int bid = blockIdx.x;
  int swzb = (bid & 7) * (NBLK / 8) + (bid >> 3);
  const int tm = swzb & (NTM - 1);
  const int tn = swzb >> 5;
  const int m0 = tm * BM, n0 = tn * BN;
  const int wr = wid >> 1, wc = wid & 1;
  const int fr = lane & 15;
  const int fg = lane >> 4;
  f32x4 acc[4][4] = {};

  for (int kt = 0; kt < K_DIM / BK; ++kt) {
    int4   breg[4];
    float4 areg[8];
#pragma unroll
    for (int p = 0; p < 4; ++p) {
      int fl = p * 256 + tid;
      int row = fl >> 3, u = fl & 7;
      breg[p] = *(const int4*)(wp + (size_t)(n0 + row) * KP + kt * (BK / 2) + u * 4);
    }
    if constexpr (MODE == 2) {
#pragma unroll
      for (int p = 0; p < 8; ++p) {
        int fl = p * 256 + tid;
        int row = fl >> 4, u = fl & 15;
        areg[p] = *(const float4*)(x + (size_t)(m0 + row) * K_DIM + kt * BK + u * 4);
      }
    }
    __syncthreads();
    if constexpr (MODE == 1) {
#pragma unroll
      for (int p = 0; p < 4; ++p) {
        int t16 = p * 256 + tid;
        int row = t16 >> 3, u = t16 & 7;
        const unsigned short* g = xb + (size_t)(m0 + row) * K_DIM + kt * BK + u * 8;
        async_copy16((char*)As + (p * 256 + wid * 64) * 16, g);
      }
    } else {
#pragma unroll
      for (int p = 0; p < 8; ++p) {
        int fl = p * 256 + tid;
        int row = fl >> 4, u = fl & 15;
        ushort4 r;
        r.x = f2bf_rne(areg[p].x); r.y = f2bf_rne(areg[p].y);
        r.z = f2bf_rne(areg[p].z); r.w = f2bf_rne(areg[p].w);
        *(ushort4*)((char*)As + row * 128 + u * 8) = r;
      }
    }
#pragma unroll
    for (int p = 0; p < 4; ++p) {
      int fl = p * 256 + tid;
      int row = fl >> 3, u = fl & 7;
      int4 b = breg[p];
      u16x8 r;
      r[0] = i2bf(sx4(b.x, 0)); r[1] = i2bf(sx4(b.x, 1));
      r[2] = i2bf(sx4(b.y, 0)); r[3] = i2bf(sx4(b.y, 1));
      r[4] = i2bf(sx4(b.z, 0)); r[5] = i2bf(sx4(b.z, 1));
      r[6] = i2bf(sx4(b.w, 0)); r[7] = i2bf(sx4(b.w, 1));
      *(u16x8*)((char*)Bs + row * 128 + u * 16) = r;
    }
    __syncthreads();
#pragma unroll
    for (int kk = 0; kk < 2; ++kk) {
      const int kb = kk * 64 + fg * 16;
      bf16x8 af[4], bfv[4];
#pragma unroll
      for (int mi = 0; mi < 4; ++mi) {
        int row = wr * 64 + mi * 16 + fr;
        af[mi] = *(const bf16x8*)((const char*)As + row * 128 + kb);
      }
#pragma unroll
      for (int ni = 0; ni < 4; ++ni) {
        int row = wc * 64 + ni * 16 + fr;
        bfv[ni] = *(const bf16x8*)((const char*)Bs + row * 128 + kb);
      }
#pragma unroll
      for (int mi = 0; mi < 4; ++mi)
#pragma unroll
        for (int ni = 0; ni < 4; ++ni)
          acc[mi][ni] = __builtin_amdgcn_mfma_f32_16x16x32_bf16(af[mi], bfv[ni], acc[mi][ni], 0, 0, 0);
    }
  }
#pragma unroll
  for (int ni = 0; ni < 4; ++ni) {
    const int o = n0 + wc * 64 + ni * 16 + fr;
    const float s = scales[o];
    const float b = bias[o];
#pragma unroll
    for (int mi = 0; mi < 4; ++mi) {
      const int mr = m0 + wr * 64 + mi * 16 + fg * 4;
#pragma unroll
      for (int r = 0; r < 4; ++r)
        out[(size_t)(mr + r) * N_DIM + o] = acc[mi][ni][r] * s + b;
    }
  }
}

extern "C" void kernel_launch(void* const* d_in, const int* in_sizes, int n_in,
                              void* d_out, int out_size, void* d_ws, size_t ws_size,
                              hipStream_t stream) {
  const float* x  = (const float*)d_in[0];
  const int*   wp = (const int*)d_in[1];
  const float* sc = (const float*)d_in[2];
  const float* bs = (const float*)d_in[3];
  float* out = (float*)d_out;

  const size_t a_bytes  = (size_t)NTM2 * NKT * 2 * HT_BYTES;  // 16,777,216
  const size_t b_bytes  = (size_t)NTN2 * NKT * 2 * HT_BYTES;  // 45,088,768
  const size_t xs_bytes = (size_t)M_DIM * 4;                  // 16 KB
  char*  wsA = (char*)d_ws;
  char*  wsB = (char*)d_ws + a_bytes;
  float* xs  = (float*)((char*)d_ws + a_bytes + b_bytes);
  float* xr  = xs + M_DIM;

  if (ws_size >= a_bytes + b_bytes + 2 * xs_bytes) {
    rowmax_x<<<M_DIM, 256, 0, stream>>>(x, xs, xr);
    quant_x_tiled<<<2048, 256, 0, stream>>>(x, xr, wsA);
    deq_w_i8<<<2048, 256, 0, stream>>>(wp, wsB);
    qgemm8i<<<NBLK2, 512, 0, stream>>>(wsA, wsB, xs, sc, bs, out);
  } else if (ws_size >= (size_t)M_DIM * K_DIM * 2) {
    cvt_x_kernel<<<2048, 256, 0, stream>>>(x, (unsigned short*)d_ws);
    qgemm_kernel<1><<<NBLK, 256, 0, stream>>>(x, (unsigned short*)d_ws, wp, sc, bs, out);
  } else {
    qgemm_kernel<2><<<NBLK, 256, 0, stream>>>(x, (unsigned short*)d_ws, wp, sc, bs, out);
  }
}

// Round 11
// 247.286 us; speedup vs baseline: 1.6833x; 1.0724x over previous
//
#include <hip/hip_runtime.h>
#include <hip/hip_bf16.h>
#include <stdint.h>

// Problem dims
#define M_DIM 4096      // 2*2048 rows of x
#define K_DIM 4096
#define N_DIM 11008
#define KP    2048      // K/2 packed int32 per w row

// ---------------- i8 4-phase 256x256 GEMM geometry (BK=64) ----------------
#define BK2   64
#define NKT   (K_DIM/BK2)        // 64 K-tiles
#define NTM2  (M_DIM/256)        // 16
#define NTN2  (N_DIM/256)        // 43
#define NBLK2 (NTM2*NTN2)        // 688  (%8==0 -> bijective XCD swizzle)
#define HT_BYTES 8192            // half-tile: 128 rows x 64 i8 (fragment-major)

// ---------------- 128x128 bf16 fallback geometry ----------------
#define BM 128
#define BN 128
#define BK 64
#define NTM (M_DIM/BM)
#define NTN (N_DIM/BN)
#define NBLK (NTM*NTN)

typedef __attribute__((ext_vector_type(8)))  short bf16x8;
typedef __attribute__((ext_vector_type(4)))  float f32x4;
typedef __attribute__((ext_vector_type(4)))  int   i32x4;
typedef __attribute__((ext_vector_type(16))) int   i32x16;
typedef __attribute__((ext_vector_type(16))) char  c8x16;
typedef __attribute__((ext_vector_type(8)))  unsigned short u16x8;

typedef const void __attribute__((address_space(1)))* gas_ptr;
typedef void __attribute__((address_space(3)))* las_ptr;

__device__ __forceinline__ void async_copy16(void* lds, const void* g) {
  __builtin_amdgcn_global_load_lds((gas_ptr)g, (las_ptr)lds, 16, 0, 0);
}

__device__ __forceinline__ unsigned short f2bf_rne(float f) {
  uint32_t u = __builtin_bit_cast(uint32_t, f);
  u += 0x7FFFu + ((u >> 16) & 1u);
  return (unsigned short)(u >> 16);
}
__device__ __forceinline__ unsigned short i2bf(int v) {
  float f = (float)v;
  return (unsigned short)(__builtin_bit_cast(uint32_t, f) >> 16);
}
__device__ __forceinline__ int sx4(int b, int which) {
  return ((int)((uint32_t)b << (28 - 4 * which))) >> 28;
}

// ---------------- i8 pre-pass ----------------
// Fragment-major half-tile image (8KB = 512 x 16B chunks):
// chunk c = sub*128 + ks*64 + kg*32 + l31 holds T[sub*32 + l31][ks*32 + kg*16 .. +16]
// (T = 128-row x 64-col i8 tile). MFMA frag read = 64 lanes x 16B contiguous -> 0 conflicts.

// Fused per-row: max|x| reduce + quantize + fragment-major scatter. x read ONCE.
// One block per row; each thread owns 16 consecutive f32 = exactly one 16B image chunk.
__global__ __launch_bounds__(256) void quant_x_fused(const float* __restrict__ x,
                                                     char* __restrict__ wsA,
                                                     float* __restrict__ xs) {
  const int grow = blockIdx.x;          // 0..M_DIM-1
  const int tid  = threadIdx.x;
  const float4* src = (const float4*)(x + (size_t)grow * K_DIM + tid * 16);
  float4 v0 = src[0], v1 = src[1], v2 = src[2], v3 = src[3];
  float vv[16] = { v0.x, v0.y, v0.z, v0.w, v1.x, v1.y, v1.z, v1.w,
                   v2.x, v2.y, v2.z, v2.w, v3.x, v3.y, v3.z, v3.w };
  float m = 0.f;
#pragma unroll
  for (int j = 0; j < 16; ++j) m = fmaxf(m, fabsf(vv[j]));
#pragma unroll
  for (int off = 32; off >= 1; off >>= 1) m = fmaxf(m, __shfl_xor(m, off));
  __shared__ float sm[4];
  if ((tid & 63) == 0) sm[tid >> 6] = m;
  __syncthreads();
  m = fmaxf(fmaxf(sm[0], sm[1]), fmaxf(sm[2], sm[3]));
  const float rs = (m > 0.f) ? 127.0f / m : 0.f;
  if (tid == 0) xs[grow] = m * (1.0f / 127.0f);
  c8x16 q;
#pragma unroll
  for (int j = 0; j < 16; ++j) q[j] = (char)__float2int_rn(vv[j] * rs);
  const int kt = tid >> 2, e = tid & 3;
  const int tm = grow >> 8, wi = grow & 255, h = wi >> 7, r = wi & 127;
  const int c = (r >> 5) * 128 + (e >> 1) * 64 + (e & 1) * 32 + (r & 31);
  *(c8x16*)(wsA + ((size_t)(tm * NKT + kt) * 2 + h) * HT_BYTES + c * 16) = q;
}

// unpack int4 -> i8 B image [tn][kt][h] (exact)
__global__ __launch_bounds__(256) void deq_w_i8(const int* __restrict__ wp,
                                                char* __restrict__ wsB) {
  const int total = NTN2 * NKT * 2 * 512;
  for (int i = blockIdx.x * blockDim.x + threadIdx.x; i < total;
       i += gridDim.x * blockDim.x) {
    int rc  = i & 511;
    int h   = (i >> 9) & 1;
    int kt  = (i >> 10) & 63;
    int tn  = i >> 16;
    int row = rc >> 2, e = rc & 3;
    const int4* src = (const int4*)(wp + (size_t)(tn * 256 + h * 128 + row) * KP + kt * 32 + e * 8);
    int4 a = src[0], b = src[1];
    c8x16 q;
    q[0]  = (char)sx4(a.x, 0); q[1]  = (char)sx4(a.x, 1);
    q[2]  = (char)sx4(a.y, 0); q[3]  = (char)sx4(a.y, 1);
    q[4]  = (char)sx4(a.z, 0); q[5]  = (char)sx4(a.z, 1);
    q[6]  = (char)sx4(a.w, 0); q[7]  = (char)sx4(a.w, 1);
    q[8]  = (char)sx4(b.x, 0); q[9]  = (char)sx4(b.x, 1);
    q[10] = (char)sx4(b.y, 0); q[11] = (char)sx4(b.y, 1);
    q[12] = (char)sx4(b.z, 0); q[13] = (char)sx4(b.z, 1);
    q[14] = (char)sx4(b.w, 0); q[15] = (char)sx4(b.w, 1);
    int c = (row >> 5) * 128 + (e >> 1) * 64 + (e & 1) * 32 + (row & 31);
    *(c8x16*)(wsB + (size_t)(i >> 9) * HT_BYTES + c * 16) = q;
  }
}

// ------- i8 4-phase 256x256 GEMM, 32x32x32_i8 (merged phases: 16-MFMA clusters) -------
__global__ __launch_bounds__(512, 2)
void qgemm8i(const char* __restrict__ wsA, const char* __restrict__ wsB,
             const float* __restrict__ xs,
             const float* __restrict__ scales, const float* __restrict__ bias,
             float* __restrict__ out) {
  __shared__ __align__(16) char smem[65536];  // 2 buf x (A 16KB + B 16KB)

  const int tid  = threadIdx.x;
  const int lane = tid & 63, wid = tid >> 6;
  const int wr = wid >> 2, wc = wid & 3;       // 2x4 wave grid; per-wave 128x64
  const int l31 = lane & 31, kg = lane >> 5;

  int bid = blockIdx.x;
  int id  = (bid & 7) * (NBLK2 / 8) + (bid >> 3);   // bijective XCD chunking
  int tm  = id & (NTM2 - 1), tn = id >> 4;          // tn-major: B panel shared per XCD

  const char* gA = wsA + (size_t)tm * (NKT * 2) * HT_BYTES;
  const char* gB = wsB + (size_t)tn * (NKT * 2) * HT_BYTES;

  // buf layout: [buf][A h0 8KB | A h1 8KB | B h0 8KB | B h1 8KB]
  const char* baseA = smem + wr * HT_BYTES + lane * 16;
  const char* baseB = smem + 16384 + (wc >> 1) * HT_BYTES + lane * 16;

#define STAGE(ldsoff, src) \
    async_copy16(smem + (ldsoff) + wid * 1024, (src) + wid * 1024 + lane * 16)
#define STAGE_A(buf, h, kt) STAGE((buf) * 32768 + (h) * HT_BYTES, gA + ((kt) * 2 + (h)) * HT_BYTES)
#define STAGE_B(buf, h, kt) STAGE((buf) * 32768 + 16384 + (h) * HT_BYTES, gB + ((kt) * 2 + (h)) * HT_BYTES)

  i32x16 acc[4][2] = {};   // [msub 0..3][nsub 0..1], 128 regs (AGPR side)
  i32x4  aS0[2][2], aS1[2][2];   // A frag sets: [msub-in-pair][ks]
  i32x4  bS0[2], bS1[2];         // B frag sets: [ks]

#define LDA_SET(dst, buf, sel) do { \
    _Pragma("unroll") for (int i = 0; i < 2; ++i) \
    _Pragma("unroll") for (int ks = 0; ks < 2; ++ks) \
      dst[i][ks] = *(const i32x4*)(baseA + (buf) * 32768 + ((sel) * 2 + i) * 2048 + ks * 1024); \
  } while (0)
#define LDB_SET(dst, buf, bn) do { \
    _Pragma("unroll") for (int ks = 0; ks < 2; ++ks) \
      dst[ks] = *(const i32x4*)(baseB + (buf) * 32768 + ((wc & 1) * 2 + (bn)) * 2048 + ks * 1024); \
  } while (0)
#define MMQ(aS, bS, sel, bn) do { \
    _Pragma("unroll") for (int ks = 0; ks < 2; ++ks) \
    _Pragma("unroll") for (int i = 0; i < 2; ++i) \
      acc[(sel) * 2 + i][bn] = __builtin_amdgcn_mfma_i32_32x32x32_i8( \
          aS[i][ks], bS[ks], acc[(sel) * 2 + i][bn], 0, 0, 0); \
  } while (0)

#define PH_BAR __builtin_amdgcn_s_barrier()
#define LGKM0 asm volatile("s_waitcnt lgkmcnt(0)" ::: "memory")
#define VMC2  asm volatile("s_waitcnt vmcnt(2)" ::: "memory")
#define PRIO1 __builtin_amdgcn_s_setprio(1)
#define PRIO0 __builtin_amdgcn_s_setprio(0)

  // Prologue: buf0 <- tile0 (4 loads), buf1.B <- tile1 (2 loads).
  STAGE_B(0, 0, 0); STAGE_B(0, 1, 0);
  STAGE_A(0, 0, 0); STAGE_A(0, 1, 0);
  STAGE_B(1, 0, 1); STAGE_B(1, 1, 1);
  VMC2;        // drain buf0's 4, keep buf1.B's 2 in flight
  PH_BAR;
  LDA_SET(aS0, 0, 0); LDB_SET(bS0, 0, 0); LDB_SET(bS1, 0, 1);

  // 4 phases/iter; vmcnt ledger (steady state): enter phA with 2 in flight
  // (prev phD's buf1.B); phA +2 (buf1.A) = 4; phB +2 = 6 -> VMC2 drains buf1's 4.
  // phC +2 = 4; phD +2 = 6 -> VMC2 drains buf0(k2)'s 4. Reads of a buffer always
  // issue AFTER the VMC2 that drains it; stages into a buffer always land >=1
  // barrier after LGKM0-verified completion of its last reads.
  for (int t = 0; t < NKT / 2; ++t) {
    const int k1 = 2 * t + 1;
    const int k2 = (2 * t + 2 < NKT) ? 2 * t + 2 : NKT - 1;  // tail clamp (never read)
    const int k3 = (2 * t + 3 < NKT) ? 2 * t + 3 : NKT - 1;

    // phA: buf0: Q(A0,B0)+Q(A0,B1); stage buf1.A(k1); issue aS1(buf0)
    LGKM0;
    PRIO1; MMQ(aS0, bS0, 0, 0); MMQ(aS0, bS1, 0, 1); PRIO0;
    STAGE_A(1, 0, k1); STAGE_A(1, 1, k1);
    LDA_SET(aS1, 0, 1);
    PH_BAR;
    // phB: buf0: Q(A1,B1)+Q(A1,B0); stage buf0.B(k2); drain buf1(k1); issue buf1 ops
    LGKM0;
    PRIO1; MMQ(aS1, bS1, 1, 1); MMQ(aS1, bS0, 1, 0); PRIO0;
    STAGE_B(0, 0, k2); STAGE_B(0, 1, k2);
    VMC2;
    LDA_SET(aS0, 1, 0); LDB_SET(bS0, 1, 0); LDB_SET(bS1, 1, 1);
    PH_BAR;
    // phC: buf1: Q(A0,B0)+Q(A0,B1); stage buf0.A(k2); issue aS1(buf1)
    LGKM0;
    PRIO1; MMQ(aS0, bS0, 0, 0); MMQ(aS0, bS1, 0, 1); PRIO0;
    STAGE_A(0, 0, k2); STAGE_A(0, 1, k2);
    LDA_SET(aS1, 1, 1);
    PH_BAR;
    // phD: buf1: Q(A1,B1)+Q(A1,B0); stage buf1.B(k3); drain buf0(k2); issue buf0 ops
    LGKM0;
    PRIO1; MMQ(aS1, bS1, 1, 1); MMQ(aS1, bS0, 1, 0); PRIO0;
    STAGE_B(1, 0, k3); STAGE_B(1, 1, k3);
    VMC2;
    LDA_SET(aS0, 0, 0); LDB_SET(bS0, 0, 0); LDB_SET(bS1, 0, 1);
    PH_BAR;
  }

  // ---- epilogue: y = acc_i32 * xs[m] * ws[o] + bias[o] ----
  // 32x32 C/D (shape-determined, dtype-independent): col = lane&31,
  // row = (reg&3) + 8*(reg>>2) + 4*(lane>>5)
  const int m0 = tm * 256, n0 = tn * 256;
#pragma unroll
  for (int ni = 0; ni < 2; ++ni) {
    const int o = n0 + wc * 64 + ni * 32 + l31;
    const float sw = scales[o];
    const float b = bias[o];
#pragma unroll
    for (int mi = 0; mi < 4; ++mi) {
      const int mrb = m0 + wr * 128 + mi * 32 + kg * 4;
#pragma unroll
      for (int r = 0; r < 16; ++r) {
        const int mr = mrb + (r & 3) + 8 * (r >> 2);
        const float y = (float)acc[mi][ni][r] * xs[mr] * sw + b;
        __builtin_nontemporal_store(y, out + (size_t)mr * N_DIM + o);
      }
    }
  }
#undef STAGE
#undef STAGE_A
#undef STAGE_B
#undef LDA_SET
#undef LDB_SET
#undef MMQ
#undef PH_BAR
#undef LGKM0
#undef VMC2
#undef PRIO1
#undef PRIO0
}

// ---------------- bf16 fallback: linear xb prepass + 128x128 GEMM ----------------
__global__ __launch_bounds__(256) void cvt_x_kernel(const float* __restrict__ x,
                                                    unsigned short* __restrict__ xb) {
  const int n4 = M_DIM * K_DIM / 4;
  int i = blockIdx.x * blockDim.x + threadIdx.x;
  const int stride = gridDim.x * blockDim.x;
  for (; i < n4; i += stride) {
    float4 v = ((const float4*)x)[i];
    ushort4 r;
    r.x = f2bf_rne(v.x); r.y = f2bf_rne(v.y);
    r.z = f2bf_rne(v.z); r.w = f2bf_rne(v.w);
    ((ushort4*)xb)[i] = r;
  }
}

template <int MODE>
__global__ __launch_bounds__(256)
void qgemm_kernel(const float* __restrict__ x, const unsigned short* __restrict__ xb,
                  const int* __restrict__ wp,
                  const float* __restrict__ scales, const float* __restrict__ bias,
                  float* __restrict__ out) {
  __shared__ __align__(16) unsigned short As[BM * BK];
  __shared__ __align__(16) unsigned short Bs[BN * BK];
  const int tid  = threadIdx.x;
  const int lane = tid & 63;
  const int wid  = tid >> 6;
  int bid = blockIdx.x;
  int swzb = (bid & 7) * (NBLK / 8) + (bid >> 3);
  const int tm = swzb & (NTM - 1);
  const int tn = swzb >> 5;
  const int m0 = tm * BM, n0 = tn * BN;
  const int wr = wid >> 1, wc = wid & 1;
  const int fr = lane & 15;
  const int fg = lane >> 4;
  f32x4 acc[4][4] = {};

  for (int kt = 0; kt < K_DIM / BK; ++kt) {
    int4   breg[4];
    float4 areg[8];
#pragma unroll
    for (int p = 0; p < 4; ++p) {
      int fl = p * 256 + tid;
      int row = fl >> 3, u = fl & 7;
      breg[p] = *(const int4*)(wp + (size_t)(n0 + row) * KP + kt * (BK / 2) + u * 4);
    }
    if constexpr (MODE == 2) {
#pragma unroll
      for (int p = 0; p < 8; ++p) {
        int fl = p * 256 + tid;
        int row = fl >> 4, u = fl & 15;
        areg[p] = *(const float4*)(x + (size_t)(m0 + row) * K_DIM + kt * BK + u * 4);
      }
    }
    __syncthreads();
    if constexpr (MODE == 1) {
#pragma unroll
      for (int p = 0; p < 4; ++p) {
        int t16 = p * 256 + tid;
        int row = t16 >> 3, u = t16 & 7;
        const unsigned short* g = xb + (size_t)(m0 + row) * K_DIM + kt * BK + u * 8;
        async_copy16((char*)As + (p * 256 + wid * 64) * 16, g);
      }
    } else {
#pragma unroll
      for (int p = 0; p < 8; ++p) {
        int fl = p * 256 + tid;
        int row = fl >> 4, u = fl & 15;
        ushort4 r;
        r.x = f2bf_rne(areg[p].x); r.y = f2bf_rne(areg[p].y);
        r.z = f2bf_rne(areg[p].z); r.w = f2bf_rne(areg[p].w);
        *(ushort4*)((char*)As + row * 128 + u * 8) = r;
      }
    }
#pragma unroll
    for (int p = 0; p < 4; ++p) {
      int fl = p * 256 + tid;
      int row = fl >> 3, u = fl & 7;
      int4 b = breg[p];
      u16x8 r;
      r[0] = i2bf(sx4(b.x, 0)); r[1] = i2bf(sx4(b.x, 1));
      r[2] = i2bf(sx4(b.y, 0)); r[3] = i2bf(sx4(b.y, 1));
      r[4] = i2bf(sx4(b.z, 0)); r[5] = i2bf(sx4(b.z, 1));
      r[6] = i2bf(sx4(b.w, 0)); r[7] = i2bf(sx4(b.w, 1));
      *(u16x8*)((char*)Bs + row * 128 + u * 16) = r;
    }
    __syncthreads();
#pragma unroll
    for (int kk = 0; kk < 2; ++kk) {
      const int kb = kk * 64 + fg * 16;
      bf16x8 af[4], bfv[4];
#pragma unroll
      for (int mi = 0; mi < 4; ++mi) {
        int row = wr * 64 + mi * 16 + fr;
        af[mi] = *(const bf16x8*)((const char*)As + row * 128 + kb);
      }
#pragma unroll
      for (int ni = 0; ni < 4; ++ni) {
        int row = wc * 64 + ni * 16 + fr;
        bfv[ni] = *(const bf16x8*)((const char*)Bs + row * 128 + kb);
      }
#pragma unroll
      for (int mi = 0; mi < 4; ++mi)
#pragma unroll
        for (int ni = 0; ni < 4; ++ni)
          acc[mi][ni] = __builtin_amdgcn_mfma_f32_16x16x32_bf16(af[mi], bfv[ni], acc[mi][ni], 0, 0, 0);
    }
  }
#pragma unroll
  for (int ni = 0; ni < 4; ++ni) {
    const int o = n0 + wc * 64 + ni * 16 + fr;
    const float s = scales[o];
    const float b = bias[o];
#pragma unroll
    for (int mi = 0; mi < 4; ++mi) {
      const int mr = m0 + wr * 64 + mi * 16 + fg * 4;
#pragma unroll
      for (int r = 0; r < 4; ++r)
        out[(size_t)(mr + r) * N_DIM + o] = acc[mi][ni][r] * s + b;
    }
  }
}

extern "C" void kernel_launch(void* const* d_in, const int* in_sizes, int n_in,
                              void* d_out, int out_size, void* d_ws, size_t ws_size,
                              hipStream_t stream) {
  const float* x  = (const float*)d_in[0];
  const int*   wp = (const int*)d_in[1];
  const float* sc = (const float*)d_in[2];
  const float* bs = (const float*)d_in[3];
  float* out = (float*)d_out;

  const size_t a_bytes  = (size_t)NTM2 * NKT * 2 * HT_BYTES;  // 16,777,216
  const size_t b_bytes  = (size_t)NTN2 * NKT * 2 * HT_BYTES;  // 45,088,768
  const size_t xs_bytes = (size_t)M_DIM * 4;                  // 16 KB
  char*  wsA = (char*)d_ws;
  char*  wsB = (char*)d_ws + a_bytes;
  float* xs  = (float*)((char*)d_ws + a_bytes + b_bytes);

  if (ws_size >= a_bytes + b_bytes + xs_bytes) {
    quant_x_fused<<<M_DIM, 256, 0, stream>>>(x, wsA, xs);
    deq_w_i8<<<2048, 256, 0, stream>>>(wp, wsB);
    qgemm8i<<<NBLK2, 512, 0, stream>>>(wsA, wsB, xs, sc, bs, out);
  } else if (ws_size >= (size_t)M_DIM * K_DIM * 2) {
    cvt_x_kernel<<<2048, 256, 0, stream>>>(x, (unsigned short*)d_ws);
    qgemm_kernel<1><<<NBLK, 256, 0, stream>>>(x, (unsigned short*)d_ws, wp, sc, bs, out);
  } else {
    qgemm_kernel<2><<<NBLK, 256, 0, stream>>>(x, (unsigned short*)d_ws, wp, sc, bs, out);
  }
}

// Round 16
// 246.827 us; speedup vs baseline: 1.6864x; 1.0019x over previous
//
#include <hip/hip_runtime.h>
#include <hip/hip_bf16.h>
#include <stdint.h>

// Problem dims
#define M_DIM 4096      // 2*2048 rows of x
#define K_DIM 4096
#define N_DIM 11008
#define KP    2048      // K/2 packed int32 per w row

// ---------------- i8 4-phase 256x256 GEMM geometry (BK=64) ----------------
#define BK2   64
#define NKT   (K_DIM/BK2)        // 64 K-tiles
#define NTM2  (M_DIM/256)        // 16
#define NTN2  (N_DIM/256)        // 43
#define NBLK2 (NTM2*NTN2)        // 688  (%8==0 -> bijective XCD swizzle)
#define HT_BYTES 8192            // half-tile: 128 rows x 64 i8 (fragment-major)

// ---------------- 128x128 bf16 fallback geometry ----------------
#define BM 128
#define BN 128
#define BK 64
#define NTM (M_DIM/BM)
#define NTN (N_DIM/BN)
#define NBLK (NTM*NTN)

typedef __attribute__((ext_vector_type(8)))  short bf16x8;
typedef __attribute__((ext_vector_type(4)))  float f32x4;
typedef __attribute__((ext_vector_type(4)))  int   i32x4;
typedef __attribute__((ext_vector_type(16))) int   i32x16;
typedef __attribute__((ext_vector_type(16))) char  c8x16;
typedef __attribute__((ext_vector_type(8)))  unsigned short u16x8;

typedef const void __attribute__((address_space(1)))* gas_ptr;
typedef void __attribute__((address_space(3)))* las_ptr;

__device__ __forceinline__ void async_copy16(void* lds, const void* g) {
  __builtin_amdgcn_global_load_lds((gas_ptr)g, (las_ptr)lds, 16, 0, 0);
}

__device__ __forceinline__ unsigned short f2bf_rne(float f) {
  uint32_t u = __builtin_bit_cast(uint32_t, f);
  u += 0x7FFFu + ((u >> 16) & 1u);
  return (unsigned short)(u >> 16);
}
__device__ __forceinline__ unsigned short i2bf(int v) {
  float f = (float)v;
  return (unsigned short)(__builtin_bit_cast(uint32_t, f) >> 16);
}
__device__ __forceinline__ int sx4(int b, int which) {
  return ((int)((uint32_t)b << (28 - 4 * which))) >> 28;
}

// ---------------- i8 pre-pass ----------------
// Fragment-major half-tile image (8KB = 512 x 16B chunks):
// chunk c = sub*128 + ks*64 + kg*32 + l31 holds T[sub*32 + l31][ks*32 + kg*16 .. +16]
// (T = 128-row x 64-col i8 tile). MFMA frag read = 64 lanes x 16B contiguous -> 0 conflicts.

// Fused per-row: max|x| reduce + quantize + fragment-major scatter. x read ONCE.
__global__ __launch_bounds__(256) void quant_x_fused(const float* __restrict__ x,
                                                     char* __restrict__ wsA,
                                                     float* __restrict__ xs) {
  const int grow = blockIdx.x;          // 0..M_DIM-1
  const int tid  = threadIdx.x;
  const float4* src = (const float4*)(x + (size_t)grow * K_DIM + tid * 16);
  float4 v0 = src[0], v1 = src[1], v2 = src[2], v3 = src[3];
  float vv[16] = { v0.x, v0.y, v0.z, v0.w, v1.x, v1.y, v1.z, v1.w,
                   v2.x, v2.y, v2.z, v2.w, v3.x, v3.y, v3.z, v3.w };
  float m = 0.f;
#pragma unroll
  for (int j = 0; j < 16; ++j) m = fmaxf(m, fabsf(vv[j]));
#pragma unroll
  for (int off = 32; off >= 1; off >>= 1) m = fmaxf(m, __shfl_xor(m, off));
  __shared__ float sm[4];
  if ((tid & 63) == 0) sm[tid >> 6] = m;
  __syncthreads();
  m = fmaxf(fmaxf(sm[0], sm[1]), fmaxf(sm[2], sm[3]));
  const float rs = (m > 0.f) ? 127.0f / m : 0.f;
  if (tid == 0) xs[grow] = m * (1.0f / 127.0f);
  c8x16 q;
#pragma unroll
  for (int j = 0; j < 16; ++j) q[j] = (char)__float2int_rn(vv[j] * rs);
  const int kt = tid >> 2, e = tid & 3;
  const int tm = grow >> 8, wi = grow & 255, h = wi >> 7, r = wi & 127;
  const int c = (r >> 5) * 128 + (e >> 1) * 64 + (e & 1) * 32 + (r & 31);
  *(c8x16*)(wsA + ((size_t)(tm * NKT + kt) * 2 + h) * HT_BYTES + c * 16) = q;
}

// unpack int4 -> i8 B image [tn][kt][h] (exact)
__global__ __launch_bounds__(256) void deq_w_i8(const int* __restrict__ wp,
                                                char* __restrict__ wsB) {
  const int total = NTN2 * NKT * 2 * 512;
  for (int i = blockIdx.x * blockDim.x + threadIdx.x; i < total;
       i += gridDim.x * blockDim.x) {
    int rc  = i & 511;
    int h   = (i >> 9) & 1;
    int kt  = (i >> 10) & 63;
    int tn  = i >> 16;
    int row = rc >> 2, e = rc & 3;
    const int4* src = (const int4*)(wp + (size_t)(tn * 256 + h * 128 + row) * KP + kt * 32 + e * 8);
    int4 a = src[0], b = src[1];
    c8x16 q;
    q[0]  = (char)sx4(a.x, 0); q[1]  = (char)sx4(a.x, 1);
    q[2]  = (char)sx4(a.y, 0); q[3]  = (char)sx4(a.y, 1);
    q[4]  = (char)sx4(a.z, 0); q[5]  = (char)sx4(a.z, 1);
    q[6]  = (char)sx4(a.w, 0); q[7]  = (char)sx4(a.w, 1);
    q[8]  = (char)sx4(b.x, 0); q[9]  = (char)sx4(b.x, 1);
    q[10] = (char)sx4(b.y, 0); q[11] = (char)sx4(b.y, 1);
    q[12] = (char)sx4(b.z, 0); q[13] = (char)sx4(b.z, 1);
    q[14] = (char)sx4(b.w, 0); q[15] = (char)sx4(b.w, 1);
    int c = (row >> 5) * 128 + (e >> 1) * 64 + (e & 1) * 32 + (row & 31);
    *(c8x16*)(wsB + (size_t)(i >> 9) * HT_BYTES + c * 16) = q;
  }
}

// ------- i8 4-phase 256x256 GEMM, 32x32x32_i8 (R11 schedule, PROVEN: 226us) -------
// NOTE: R12-R15 all tried to hoist phA/phC reads+stages before the MFMA cluster;
// all three fence-complete variants failed with intermittent absmax ~3.2-3.6.
// The MFMA-first ordering below is load-bearing. Do not reorder.
__global__ __launch_bounds__(512, 2)
void qgemm8i(const char* __restrict__ wsA, const char* __restrict__ wsB,
             const float* __restrict__ xs,
             const float* __restrict__ scales, const float* __restrict__ bias,
             float* __restrict__ out) {
  __shared__ __align__(16) char smem[65536];  // 2 buf x (A 16KB + B 16KB)

  const int tid  = threadIdx.x;
  const int lane = tid & 63, wid = tid >> 6;
  const int wr = wid >> 2, wc = wid & 3;       // 2x4 wave grid; per-wave 128x64
  const int l31 = lane & 31, kg = lane >> 5;

  int bid = blockIdx.x;
  int id  = (bid & 7) * (NBLK2 / 8) + (bid >> 3);   // bijective XCD chunking
  int tm  = id & (NTM2 - 1), tn = id >> 4;          // tn-major: B panel shared per XCD

  const char* gA = wsA + (size_t)tm * (NKT * 2) * HT_BYTES;
  const char* gB = wsB + (size_t)tn * (NKT * 2) * HT_BYTES;

  // buf layout: [buf][A h0 8KB | A h1 8KB | B h0 8KB | B h1 8KB]
  const char* baseA = smem + wr * HT_BYTES + lane * 16;
  const char* baseB = smem + 16384 + (wc >> 1) * HT_BYTES + lane * 16;

#define STAGE(ldsoff, src) \
    async_copy16(smem + (ldsoff) + wid * 1024, (src) + wid * 1024 + lane * 16)
#define STAGE_A(buf, h, kt) STAGE((buf) * 32768 + (h) * HT_BYTES, gA + ((kt) * 2 + (h)) * HT_BYTES)
#define STAGE_B(buf, h, kt) STAGE((buf) * 32768 + 16384 + (h) * HT_BYTES, gB + ((kt) * 2 + (h)) * HT_BYTES)

  i32x16 acc[4][2] = {};   // [msub 0..3][nsub 0..1], 128 regs (AGPR side)
  i32x4  aS0[2][2], aS1[2][2];   // A frag sets: [msub-in-pair][ks]
  i32x4  bS0[2], bS1[2];         // B frag sets: [ks]

#define LDA_SET(dst, buf, sel) do { \
    _Pragma("unroll") for (int i = 0; i < 2; ++i) \
    _Pragma("unroll") for (int ks = 0; ks < 2; ++ks) \
      dst[i][ks] = *(const i32x4*)(baseA + (buf) * 32768 + ((sel) * 2 + i) * 2048 + ks * 1024); \
  } while (0)
#define LDB_SET(dst, buf, bn) do { \
    _Pragma("unroll") for (int ks = 0; ks < 2; ++ks) \
      dst[ks] = *(const i32x4*)(baseB + (buf) * 32768 + ((wc & 1) * 2 + (bn)) * 2048 + ks * 1024); \
  } while (0)
#define MMQ(aS, bS, sel, bn) do { \
    _Pragma("unroll") for (int ks = 0; ks < 2; ++ks) \
    _Pragma("unroll") for (int i = 0; i < 2; ++i) \
      acc[(sel) * 2 + i][bn] = __builtin_amdgcn_mfma_i32_32x32x32_i8( \
          aS[i][ks], bS[ks], acc[(sel) * 2 + i][bn], 0, 0, 0); \
  } while (0)

#define PH_BAR __builtin_amdgcn_s_barrier()
#define LGKM0 asm volatile("s_waitcnt lgkmcnt(0)" ::: "memory")
#define VMC2  asm volatile("s_waitcnt vmcnt(2)" ::: "memory")
#define PRIO1 __builtin_amdgcn_s_setprio(1)
#define PRIO0 __builtin_amdgcn_s_setprio(0)

  // Prologue: buf0 <- tile0 (4 loads), buf1.B <- tile1 (2 loads).
  STAGE_B(0, 0, 0); STAGE_B(0, 1, 0);
  STAGE_A(0, 0, 0); STAGE_A(0, 1, 0);
  STAGE_B(1, 0, 1); STAGE_B(1, 1, 1);
  VMC2;        // drain buf0's 4, keep buf1.B's 2 in flight
  PH_BAR;
  LDA_SET(aS0, 0, 0); LDB_SET(bS0, 0, 0); LDB_SET(bS1, 0, 1);

  // 4 phases/iter; vmcnt ledger (steady state): enter phA with 2 in flight
  // (prev phD's buf1.B); phA +2 (buf1.A) = 4; phB +2 = 6 -> VMC2 drains buf1's 4.
  // phC +2 = 4; phD +2 = 6 -> VMC2 drains buf0(k2)'s 4. Reads of a buffer always
  // issue AFTER the VMC2 that drains it; stages into a buffer always land >=1
  // barrier after LGKM0-verified completion of its last reads.
  for (int t = 0; t < NKT / 2; ++t) {
    const int k1 = 2 * t + 1;
    const int k2 = (2 * t + 2 < NKT) ? 2 * t + 2 : NKT - 1;  // tail clamp (never read)
    const int k3 = (2 * t + 3 < NKT) ? 2 * t + 3 : NKT - 1;

    // phA: buf0: Q(A0,B0)+Q(A0,B1); stage buf1.A(k1); issue aS1(buf0)
    LGKM0;
    PRIO1; MMQ(aS0, bS0, 0, 0); MMQ(aS0, bS1, 0, 1); PRIO0;
    STAGE_A(1, 0, k1); STAGE_A(1, 1, k1);
    LDA_SET(aS1, 0, 1);
    PH_BAR;
    // phB: buf0: Q(A1,B1)+Q(A1,B0); stage buf0.B(k2); drain buf1(k1); issue buf1 ops
    LGKM0;
    PRIO1; MMQ(aS1, bS1, 1, 1); MMQ(aS1, bS0, 1, 0); PRIO0;
    STAGE_B(0, 0, k2); STAGE_B(0, 1, k2);
    VMC2;
    LDA_SET(aS0, 1, 0); LDB_SET(bS0, 1, 0); LDB_SET(bS1, 1, 1);
    PH_BAR;
    // phC: buf1: Q(A0,B0)+Q(A0,B1); stage buf0.A(k2); issue aS1(buf1)
    LGKM0;
    PRIO1; MMQ(aS0, bS0, 0, 0); MMQ(aS0, bS1, 0, 1); PRIO0;
    STAGE_A(0, 0, k2); STAGE_A(0, 1, k2);
    LDA_SET(aS1, 1, 1);
    PH_BAR;
    // phD: buf1: Q(A1,B1)+Q(A1,B0); stage buf1.B(k3); drain buf0(k2); issue buf0 ops
    LGKM0;
    PRIO1; MMQ(aS1, bS1, 1, 1); MMQ(aS1, bS0, 1, 0); PRIO0;
    STAGE_B(1, 0, k3); STAGE_B(1, 1, k3);
    VMC2;
    LDA_SET(aS0, 0, 0); LDB_SET(bS0, 0, 0); LDB_SET(bS1, 0, 1);
    PH_BAR;
  }

  // ---- epilogue: y = acc_i32 * xs[m] * ws[o] + bias[o] ----
  // 32x32 C/D (shape-determined, dtype-independent): col = lane&31,
  // row = (reg&3) + 8*(reg>>2) + 4*(lane>>5)
  const int m0 = tm * 256, n0 = tn * 256;
#pragma unroll
  for (int ni = 0; ni < 2; ++ni) {
    const int o = n0 + wc * 64 + ni * 32 + l31;
    const float sw = scales[o];
    const float b = bias[o];
#pragma unroll
    for (int mi = 0; mi < 4; ++mi) {
      const int mrb = m0 + wr * 128 + mi * 32 + kg * 4;
#pragma unroll
      for (int r = 0; r < 16; ++r) {
        const int mr = mrb + (r & 3) + 8 * (r >> 2);
        const float y = (float)acc[mi][ni][r] * xs[mr] * sw + b;
        __builtin_nontemporal_store(y, out + (size_t)mr * N_DIM + o);
      }
    }
  }
#undef STAGE
#undef STAGE_A
#undef STAGE_B
#undef LDA_SET
#undef LDB_SET
#undef MMQ
#undef PH_BAR
#undef LGKM0
#undef VMC2
#undef PRIO1
#undef PRIO0
}

// ---------------- bf16 fallback: linear xb prepass + 128x128 GEMM ----------------
__global__ __launch_bounds__(256) void cvt_x_kernel(const float* __restrict__ x,
                                                    unsigned short* __restrict__ xb) {
  const int n4 = M_DIM * K_DIM / 4;
  int i = blockIdx.x * blockDim.x + threadIdx.x;
  const int stride = gridDim.x * blockDim.x;
  for (; i < n4; i += stride) {
    float4 v = ((const float4*)x)[i];
    ushort4 r;
    r.x = f2bf_rne(v.x); r.y = f2bf_rne(v.y);
    r.z = f2bf_rne(v.z); r.w = f2bf_rne(v.w);
    ((ushort4*)xb)[i] = r;
  }
}

template <int MODE>
__global__ __launch_bounds__(256)
void qgemm_kernel(const float* __restrict__ x, const unsigned short* __restrict__ xb,
                  const int* __restrict__ wp,
                  const float* __restrict__ scales, const float* __restrict__ bias,
                  float* __restrict__ out) {
  __shared__ __align__(16) unsigned short As[BM * BK];
  __shared__ __align__(16) unsigned short Bs[BN * BK];
  const int tid  = threadIdx.x;
  const int lane = tid & 63;
  const int wid  = tid >> 6;
  int bid = blockIdx.x;
  int swzb = (bid & 7) * (NBLK / 8) + (bid >> 3);
  const int tm = swzb & (NTM - 1);
  const int tn = swzb >> 5;
  const int m0 = tm * BM, n0 = tn * BN;
  const int wr = wid >> 1, wc = wid & 1;
  const int fr = lane & 15;
  const int fg = lane >> 4;
  f32x4 acc[4][4] = {};

  for (int kt = 0; kt < K_DIM / BK; ++kt) {
    int4   breg[4];
    float4 areg[8];
#pragma unroll
    for (int p = 0; p < 4; ++p) {
      int fl = p * 256 + tid;
      int row = fl >> 3, u = fl & 7;
      breg[p] = *(const int4*)(wp + (size_t)(n0 + row) * KP + kt * (BK / 2) + u * 4);
    }
    if constexpr (MODE == 2) {
#pragma unroll
      for (int p = 0; p < 8; ++p) {
        int fl = p * 256 + tid;
        int row = fl >> 4, u = fl & 15;
        areg[p] = *(const float4*)(x + (size_t)(m0 + row) * K_DIM + kt * BK + u * 4);
      }
    }
    __syncthreads();
    if constexpr (MODE == 1) {
#pragma unroll
      for (int p = 0; p < 4; ++p) {
        int t16 = p * 256 + tid;
        int row = t16 >> 3, u = t16 & 7;
        const unsigned short* g = xb + (size_t)(m0 + row) * K_DIM + kt * BK + u * 8;
        async_copy16((char*)As + (p * 256 + wid * 64) * 16, g);
      }
    } else {
#pragma unroll
      for (int p = 0; p < 8; ++p) {
        int fl = p * 256 + tid;
        int row = fl >> 4, u = fl & 15;
        ushort4 r;
        r.x = f2bf_rne(areg[p].x); r.y = f2bf_rne(areg[p].y);
        r.z = f2bf_rne(areg[p].z); r.w = f2bf_rne(areg[p].w);
        *(ushort4*)((char*)As + row * 128 + u * 8) = r;
      }
    }
#pragma unroll
    for (int p = 0; p < 4; ++p) {
      int fl = p * 256 + tid;
      int row = fl >> 3, u = fl & 7;
      int4 b = breg[p];
      u16x8 r;
      r[0] = i2bf(sx4(b.x, 0)); r[1] = i2bf(sx4(b.x, 1));
      r[2] = i2bf(sx4(b.y, 0)); r[3] = i2bf(sx4(b.y, 1));
      r[4] = i2bf(sx4(b.z, 0)); r[5] = i2bf(sx4(b.z, 1));
      r[6] = i2bf(sx4(b.w, 0)); r[7] = i2bf(sx4(b.w, 1));
      *(u16x8*)((char*)Bs + row * 128 + u * 16) = r;
    }
    __syncthreads();
#pragma unroll
    for (int kk = 0; kk < 2; ++kk) {
      const int kb = kk * 64 + fg * 16;
      bf16x8 af[4], bfv[4];
#pragma unroll
      for (int mi = 0; mi < 4; ++mi) {
        int row = wr * 64 + mi * 16 + fr;
        af[mi] = *(const bf16x8*)((const char*)As + row * 128 + kb);
      }
#pragma unroll
      for (int ni = 0; ni < 4; ++ni) {
        int row = wc * 64 + ni * 16 + fr;
        bfv[ni] = *(const bf16x8*)((const char*)Bs + row * 128 + kb);
      }
#pragma unroll
      for (int mi = 0; mi < 4; ++mi)
#pragma unroll
        for (int ni = 0; ni < 4; ++ni)
          acc[mi][ni] = __builtin_amdgcn_mfma_f32_16x16x32_bf16(af[mi], bfv[ni], acc[mi][ni], 0, 0, 0);
    }
  }
#pragma unroll
  for (int ni = 0; ni < 4; ++ni) {
    const int o = n0 + wc * 64 + ni * 16 + fr;
    const float s = scales[o];
    const float b = bias[o];
#pragma unroll
    for (int mi = 0; mi < 4; ++mi) {
      const int mr = m0 + wr * 64 + mi * 16 + fg * 4;
#pragma unroll
      for (int r = 0; r < 4; ++r)
        out[(size_t)(mr + r) * N_DIM + o] = acc[mi][ni][r] * s + b;
    }
  }
}

extern "C" void kernel_launch(void* const* d_in, const int* in_sizes, int n_in,
                              void* d_out, int out_size, void* d_ws, size_t ws_size,
                              hipStream_t stream) {
  const float* x  = (const float*)d_in[0];
  const int*   wp = (const int*)d_in[1];
  const float* sc = (const float*)d_in[2];
  const float* bs = (const float*)d_in[3];
  float* out = (float*)d_out;

  const size_t a_bytes  = (size_t)NTM2 * NKT * 2 * HT_BYTES;  // 16,777,216
  const size_t b_bytes  = (size_t)NTN2 * NKT * 2 * HT_BYTES;  // 45,088,768
  const size_t xs_bytes = (size_t)M_DIM * 4;                  // 16 KB
  char*  wsA = (char*)d_ws;
  char*  wsB = (char*)d_ws + a_bytes;
  float* xs  = (float*)((char*)d_ws + a_bytes + b_bytes);

  if (ws_size >= a_bytes + b_bytes + xs_bytes) {
    quant_x_fused<<<M_DIM, 256, 0, stream>>>(x, wsA, xs);
    deq_w_i8<<<2048, 256, 0, stream>>>(wp, wsB);
    qgemm8i<<<NBLK2, 512, 0, stream>>>(wsA, wsB, xs, sc, bs, out);
  } else if (ws_size >= (size_t)M_DIM * K_DIM * 2) {
    cvt_x_kernel<<<2048, 256, 0, stream>>>(x, (unsigned short*)d_ws);
    qgemm_kernel<1><<<NBLK, 256, 0, stream>>>(x, (unsigned short*)d_ws, wp, sc, bs, out);
  } else {
    qgemm_kernel<2><<<NBLK, 256, 0, stream>>>(x, (unsigned short*)d_ws, wp, sc, bs, out);
  }
}